// Round 10
// baseline (457.898 us; speedup 1.0000x reference)
//
#include <hip/hip_runtime.h>
#include <stdint.h>

// Problem constants
#define BB    8
#define HH    16
#define SS    640
#define STOK  512
#define STMN  128
#define HD    64
#define DIM   1024
#define NEGINF (-1e18f)

typedef short v8s __attribute__((ext_vector_type(8)));
typedef float v4f __attribute__((ext_vector_type(4)));

static __device__ __forceinline__ ushort f2b(float f) {
    union { float f; uint32_t u; } x; x.f = f;
    uint32_t u = (x.u + 0x7FFFu + ((x.u >> 16) & 1u)) >> 16;
    return (ushort)u;
}
static __device__ __forceinline__ float b2f(ushort h) {
    union { uint32_t u; float f; } x; x.u = ((uint32_t)h) << 16;
    return x.f;
}

// ---------------------------------------------------------------------------
// Kernel A0: convert x (stok||stm, [5120][1024]) and qkv_w ([3072][1024]) to
// bf16; split out_w ([1024][1024]) into bf16 hi/lo pair.  Pure streaming.
// ---------------------------------------------------------------------------
__global__ __launch_bounds__(256) void cvt_bf16(
    const float* __restrict__ stok, const float* __restrict__ stm,
    const float* __restrict__ W, const float* __restrict__ Wo,
    ushort* __restrict__ xb, ushort* __restrict__ Wb,
    ushort* __restrict__ Woh, ushort* __restrict__ Wol)
{
    const int i = blockIdx.x * 256 + threadIdx.x;
    const int XG = 5120 * 256;                      // float4-groups in x
    const int WG = 3072 * 256;                      // float4-groups in qkv_w
    if (i < XG + WG) {
        float4 v; ushort* dst;
        if (i < XG) {
            int row = i >> 8, g = i & 255;
            int b = row / SS, s = row % SS;
            const float* src = (s < STOK)
                ? stok + ((size_t)b * STOK + s) * DIM
                : stm  + ((size_t)b * STMN + (s - STOK)) * DIM;
            v = *reinterpret_cast<const float4*>(src + g * 4);
            dst = xb + (size_t)row * DIM + g * 4;
        } else {
            int j = i - XG;
            int row = j >> 8, g = j & 255;
            v = *reinterpret_cast<const float4*>(W + (size_t)row * DIM + g * 4);
            dst = Wb + (size_t)row * DIM + g * 4;
        }
        ushort4 o;
        o.x = f2b(v.x); o.y = f2b(v.y); o.z = f2b(v.z); o.w = f2b(v.w);
        *reinterpret_cast<ushort4*>(dst) = o;
    } else {
        int j = i - XG - WG;
        int row = j >> 8, g = j & 255;
        float4 v = *reinterpret_cast<const float4*>(Wo + (size_t)row * DIM + g * 4);
        ushort4 hi, lo;
        hi.x = f2b(v.x); lo.x = f2b(v.x - b2f(hi.x));
        hi.y = f2b(v.y); lo.y = f2b(v.y - b2f(hi.y));
        hi.z = f2b(v.z); lo.z = f2b(v.z - b2f(hi.z));
        hi.w = f2b(v.w); lo.w = f2b(v.w - b2f(hi.w));
        *reinterpret_cast<ushort4*>(&Woh[(size_t)row * DIM + g * 4]) = hi;
        *reinterpret_cast<ushort4*>(&Wol[(size_t)row * DIM + g * 4]) = lo;
    }
}

// ---------------------------------------------------------------------------
// Kernel A: QKV projection via MFMA, barrier-free direct-global fragments.
// Block = 128x128 output tile; 4 waves (2x2), each 64x64 = 4x4 fragments.
// Epilogue: bf16 q[bh][s][d] (pre-scaled 1/8), k[bh][s][d], vT[bh][d][s].
// ---------------------------------------------------------------------------
__global__ __launch_bounds__(256, 4) void gemm_qkv_mfma(
    const ushort* __restrict__ xb, const ushort* __restrict__ Wb,
    const float* __restrict__ bias,
    ushort* __restrict__ qb, ushort* __restrict__ kb, ushort* __restrict__ vtb)
{
    const int t = threadIdx.x, lane = t & 63, w = t >> 6;
    const int swz = ((blockIdx.x & 7) * 120) + (blockIdx.x >> 3);
    const int nt = swz / 40, mt = swz % 40;
    const int mb = mt * 128, nb = nt * 128;
    const int wm = (w >> 1) * 64, wn = (w & 1) * 64;
    const int lg = lane >> 4, lc = lane & 15;

    const ushort* pA[4];
    const ushort* pB[4];
#pragma unroll
    for (int i = 0; i < 4; ++i) {
        pA[i] = xb + (size_t)(mb + wm + i * 16 + lc) * DIM + lg * 8;
        pB[i] = Wb + (size_t)(nb + wn + i * 16 + lc) * DIM + lg * 8;
    }

    v4f acc[4][4];
#pragma unroll
    for (int i = 0; i < 4; ++i)
#pragma unroll
        for (int j = 0; j < 4; ++j) acc[i][j] = (v4f){0.f, 0.f, 0.f, 0.f};

#pragma unroll 2
    for (int kt = 0; kt < 32; ++kt) {
        const int ko = kt * 32;
        v8s af[4], bf[4];
#pragma unroll
        for (int i = 0; i < 4; ++i) af[i] = *reinterpret_cast<const v8s*>(pA[i] + ko);
#pragma unroll
        for (int i = 0; i < 4; ++i) bf[i] = *reinterpret_cast<const v8s*>(pB[i] + ko);
#pragma unroll
        for (int i = 0; i < 4; ++i)
#pragma unroll
            for (int j = 0; j < 4; ++j)
                acc[i][j] = __builtin_amdgcn_mfma_f32_16x16x32_bf16(af[i], bf[j], acc[i][j], 0, 0, 0);
    }

    const int nregion = nb >> 10;                  // 0=q 1=k 2=v (tile within one region)
    if (nregion < 2) {
        ushort* dst = nregion ? kb : qb;
        const float scale = nregion ? 1.0f : 0.125f;
#pragma unroll
        for (int j = 0; j < 4; ++j) {
            int n = nb + wn + j * 16 + lc;
            int nn = n & 1023, h = nn >> 6, d = nn & 63;
            float bi = bias[n];
#pragma unroll
            for (int i = 0; i < 4; ++i) {
                int m0 = mb + wm + i * 16 + lg * 4;
                int b = m0 / SS, s0 = m0 % SS;
                size_t base = (((size_t)b * HH + h) * SS + s0) * HD + d;
#pragma unroll
                for (int r = 0; r < 4; ++r)
                    dst[base + (size_t)r * HD] = f2b((acc[i][j][r] + bi) * scale);
            }
        }
    } else {
#pragma unroll
        for (int j = 0; j < 4; ++j) {
            int n = nb + wn + j * 16 + lc;
            int nn = n & 1023, h = nn >> 6, d = nn & 63;
            float bi = bias[n];
#pragma unroll
            for (int i = 0; i < 4; ++i) {
                int m0 = mb + wm + i * 16 + lg * 4;   // 4 consecutive s, same b
                int b = m0 / SS, s0 = m0 % SS;
                ushort4 pk;
                pk.x = f2b(acc[i][j][0] + bi);
                pk.y = f2b(acc[i][j][1] + bi);
                pk.z = f2b(acc[i][j][2] + bi);
                pk.w = f2b(acc[i][j][3] + bi);
                *reinterpret_cast<ushort4*>(
                    &vtb[(((size_t)b * HH + h) * HD + d) * SS + s0]) = pk;
            }
        }
    }
}

// ---------------------------------------------------------------------------
// Kernel C: out projection via MFMA, double-bf16 (hi/lo), fused passes:
// per K-step load ah/al/bh/bl and fire 24 MFMAs (hh, lh, hl) -> 3x ILP.
// m-major XCD swizzle: each XCD owns 1/8 of ctx rows, re-reads only W (4MB).
// Block = 64x128 tile (640 blocks); 4 waves 2x2, wave 32x64 = 2x4 frags.
// ---------------------------------------------------------------------------
__global__ __launch_bounds__(256, 4) void gemm_out_mfma(
    const ushort* __restrict__ Xh, const ushort* __restrict__ Xl,
    const ushort* __restrict__ Wh, const ushort* __restrict__ Wl,
    const float* __restrict__ bias, float* __restrict__ out)
{
    const int t = threadIdx.x, lane = t & 63, w = t >> 6;
    // m-major: XCD k owns swz in [80k, 80k+80) -> mt in [10k,10k+10), all nt
    const int swz = ((blockIdx.x & 7) * 80) + (blockIdx.x >> 3);
    const int mt = swz >> 3, nt = swz & 7;
    const int mb = mt * 64, nb = nt * 128;
    const int wm = (w >> 1) * 32, wn = (w & 1) * 64;
    const int lg = lane >> 4, lc = lane & 15;

    size_t aoff[2];
    size_t boff[4];
#pragma unroll
    for (int i = 0; i < 2; ++i)
        aoff[i] = (size_t)(mb + wm + i * 16 + lc) * DIM + lg * 8;
#pragma unroll
    for (int j = 0; j < 4; ++j)
        boff[j] = (size_t)(nb + wn + j * 16 + lc) * DIM + lg * 8;

    v4f acc[2][4];
#pragma unroll
    for (int i = 0; i < 2; ++i)
#pragma unroll
        for (int j = 0; j < 4; ++j) acc[i][j] = (v4f){0.f, 0.f, 0.f, 0.f};

#pragma unroll 2
    for (int kt = 0; kt < 32; ++kt) {
        const int ko = kt * 32;
        v8s ah[2], al[2], bh[4], bl[4];
#pragma unroll
        for (int i = 0; i < 2; ++i) {
            ah[i] = *reinterpret_cast<const v8s*>(Xh + aoff[i] + ko);
            al[i] = *reinterpret_cast<const v8s*>(Xl + aoff[i] + ko);
        }
#pragma unroll
        for (int j = 0; j < 4; ++j) {
            bh[j] = *reinterpret_cast<const v8s*>(Wh + boff[j] + ko);
            bl[j] = *reinterpret_cast<const v8s*>(Wl + boff[j] + ko);
        }
#pragma unroll
        for (int i = 0; i < 2; ++i)
#pragma unroll
            for (int j = 0; j < 4; ++j)
                acc[i][j] = __builtin_amdgcn_mfma_f32_16x16x32_bf16(ah[i], bh[j], acc[i][j], 0, 0, 0);
#pragma unroll
        for (int i = 0; i < 2; ++i)
#pragma unroll
            for (int j = 0; j < 4; ++j)
                acc[i][j] = __builtin_amdgcn_mfma_f32_16x16x32_bf16(al[i], bh[j], acc[i][j], 0, 0, 0);
#pragma unroll
        for (int i = 0; i < 2; ++i)
#pragma unroll
            for (int j = 0; j < 4; ++j)
                acc[i][j] = __builtin_amdgcn_mfma_f32_16x16x32_bf16(ah[i], bl[j], acc[i][j], 0, 0, 0);
    }

#pragma unroll
    for (int j = 0; j < 4; ++j) {
        int n = nb + wn + j * 16 + lc;
        float bi = bias[n];
#pragma unroll
        for (int i = 0; i < 2; ++i) {
            int m0 = mb + wm + i * 16 + lg * 4;
#pragma unroll
            for (int r = 0; r < 4; ++r)
                out[(size_t)(m0 + r) * DIM + n] = acc[i][j][r] + bi;
        }
    }
}

// ---------------------------------------------------------------------------
// Kernel B: barrier-free MFMA attention, occupancy-optimized.
// Block = 128 threads (2 waves) x 32 q-rows; grid 2560.  18.4 KB LDS ->
// ~8 blocks/CU (16 waves/CU) to cover the per-wave latency stalls that
// capped the 4-wave/64-row version at ~2 blocks/CU.  Per-wave structure
// identical to the proven r7 body (direct-global K/V frags, two sweeps).
// ---------------------------------------------------------------------------
__global__ __launch_bounds__(128, 6) void attn_mfma(
    const ushort* __restrict__ qb, const ushort* __restrict__ kb,
    const ushort* __restrict__ vtb,
    const uint8_t* __restrict__ mtok, const uint8_t* __restrict__ mstm,
    const float* __restrict__ relk, const float* __restrict__ relv,
    const float* __restrict__ smk,  const float* __restrict__ smv,
    float* __restrict__ attn_out,
    ushort* __restrict__ ctxh, ushort* __restrict__ ctxl)
{
    __shared__ ushort qrel[32][72];
    __shared__ ushort Plds[64][72];    // rows 0..31: P; all 64 rows: relv^T
    __shared__ ushort wbin[32][72];

    const int t    = threadIdx.x;
    const int lane = t & 63, w = t >> 6;
    const int swz  = ((blockIdx.x & 7) * 320) + (blockIdx.x >> 3);  // XCD-contiguous
    const int qt = swz % 20, bh = swz / 20;
    const int b = bh >> 4, h = bh & 15;
    const int qbase = qt * 32;
    const bool qstm = (qt >= 16);
    const size_t bhoff = (size_t)bh * (SS * HD);
    const int wq = w * 16, lg = lane >> 4, lc = lane & 15;
    const int RR = qstm ? 16 : 32;
    const int NV = qstm ? 33 : 65;
    const float* tabk = qstm ? smk : relk;

    // zero this wave's wbin rows (own rows only -> no barrier needed)
    for (int i = lane; i < 16 * 36; i += 64) {
        int r = i / 36, c = i - r * 36;
        *reinterpret_cast<uint32_t*>(&wbin[wq + r][c * 2]) = 0u;
    }

    // stm blocks: zero attn cols 0..511 (scores are -inf there)
    if (qstm) {
        float4 z = make_float4(0.f, 0.f, 0.f, 0.f);
        float* dst = attn_out + ((size_t)bh * SS + qbase) * SS;
        for (int idx = t; idx < 32 * 128; idx += 128) {
            int r = idx >> 7, c4 = idx & 127;
            *reinterpret_cast<float4*>(&dst[(size_t)r * SS + c4 * 4]) = z;
        }
    }

    // per-lane pad-mask bitmask: bit kt*4+sub covers key kg = kt*64+sub*16+lc
    uint64_t mkbits = 0;
#pragma unroll
    for (int kt = 0; kt < 10; ++kt)
#pragma unroll
        for (int sub = 0; sub < 4; ++sub) {
            int kg = kt * 64 + sub * 16 + lc;
            uint8_t m = (kg < STOK) ? mtok[b * STOK + kg] : mstm[b * STMN + kg - STOK];
            mkbits |= ((uint64_t)(m ? 1u : 0u)) << (kt * 4 + sub);
        }

    // Q A-fragments straight from global (row = qbase+wq+lc)
    const int qrow = qbase + wq + lc;
    v8s aq0 = *reinterpret_cast<const v8s*>(&qb[bhoff + (size_t)qrow * HD + lg * 8]);
    v8s aq1 = *reinterpret_cast<const v8s*>(&qb[bhoff + (size_t)qrow * HD + 32 + lg * 8]);

    // qrel[i][v] = q_i . rel_emb_k[v] via MFMA (wave's own 16 rows)
    {
        const int ndt = qstm ? 2 : 4;
        for (int dt = 0; dt < ndt; ++dt) {
            const float* rp = tabk + (size_t)(dt * 16 + lc) * HD;
            v8s bk0, bk1;
#pragma unroll
            for (int j = 0; j < 8; ++j) {
                bk0[j] = (short)f2b(rp[lg * 8 + j]);
                bk1[j] = (short)f2b(rp[32 + lg * 8 + j]);
            }
            v4f c4 = {0.f, 0.f, 0.f, 0.f};
            c4 = __builtin_amdgcn_mfma_f32_16x16x32_bf16(aq0, bk0, c4, 0, 0, 0);
            c4 = __builtin_amdgcn_mfma_f32_16x16x32_bf16(aq1, bk1, c4, 0, 0, 0);
#pragma unroll
            for (int r = 0; r < 4; ++r)
                qrel[wq + lg * 4 + r][dt * 16 + lc] = f2b(c4[r]);
        }
        // last column v = NV-1 (row NV-1 of table), scalar partial + shfl
        const float* rp = tabk + (size_t)(NV - 1) * HD;
        float part = 0.f;
#pragma unroll
        for (int j = 0; j < 8; ++j) {
            part += b2f((ushort)aq0[j]) * rp[lg * 8 + j];
            part += b2f((ushort)aq1[j]) * rp[32 + lg * 8 + j];
        }
        part += __shfl_xor(part, 16);
        part += __shfl_xor(part, 32);
        if (lg == 0) qrel[wq + lc][NV - 1] = f2b(part);
    }

    // register-cached saturated rel values (clamp hits these for ~85% of keys)
    float relL[4], relR[4];
#pragma unroll
    for (int r = 0; r < 4; ++r) {
        int lq = wq + lg * 4 + r;
        relL[r] = b2f(qrel[lq][0]);
        relR[r] = b2f(qrel[lq][2 * RR]);
    }

    const int tile0 = qstm ? 8 : 0;
    float lsum[4] = {0.f, 0.f, 0.f, 0.f};

    // ---- sweep 1: exp-sums (K-frags from global, no barriers) ----
    for (int kt = tile0; kt < 10; ++kt) {
        const ushort* kbase = kb + bhoff + (size_t)(kt * 64) * HD;
        const bool dorel = qstm || (kt < 8);
        const uint32_t nib = (uint32_t)(mkbits >> (kt * 4));
#pragma unroll
        for (int sub = 0; sub < 4; ++sub) {
            v8s bk0 = *reinterpret_cast<const v8s*>(&kbase[(sub * 16 + lc) * HD + lg * 8]);
            v8s bk1 = *reinterpret_cast<const v8s*>(&kbase[(sub * 16 + lc) * HD + 32 + lg * 8]);
            v4f c4 = {0.f, 0.f, 0.f, 0.f};
            c4 = __builtin_amdgcn_mfma_f32_16x16x32_bf16(aq0, bk0, c4, 0, 0, 0);
            c4 = __builtin_amdgcn_mfma_f32_16x16x32_bf16(aq1, bk1, c4, 0, 0, 0);
            int kg = kt * 64 + sub * 16 + lc;
            const bool mk = (nib >> sub) & 1;
#pragma unroll
            for (int r = 0; r < 4; ++r) {
                int lq = wq + lg * 4 + r;
                float val = c4[r];
                if (dorel) {
                    int dlt = kg - (qbase + lq);
                    float relv;
                    if (dlt > -RR && dlt < RR)
                        relv = b2f(qrel[lq][dlt + RR]);     // band only
                    else
                        relv = (dlt <= -RR) ? relL[r] : relR[r];
                    val += relv;
                }
                if (mk) val = NEGINF;
                lsum[r] += __expf(val);
            }
        }
    }

    float invl[4];
#pragma unroll
    for (int r = 0; r < 4; ++r) {
        float s = lsum[r];
        s += __shfl_xor(s, 1); s += __shfl_xor(s, 2);
        s += __shfl_xor(s, 4); s += __shfl_xor(s, 8);
        invl[r] = 1.f / s;
    }

    v4f o[4];
#pragma unroll
    for (int dt = 0; dt < 4; ++dt) o[dt] = (v4f){0.f, 0.f, 0.f, 0.f};
    float e0l[4] = {0.f, 0.f, 0.f, 0.f};
    float e1l[4] = {0.f, 0.f, 0.f, 0.f};
    float* arow = attn_out + ((size_t)bh * SS + qbase) * SS;

    // ---- sweep 2: probs + attn write + bins + PV (no barriers) ----
    for (int kt = tile0; kt < 10; ++kt) {
        const ushort* kbase = kb + bhoff + (size_t)(kt * 64) * HD;
        const bool dorel = qstm || (kt < 8);
        const uint32_t nib = (uint32_t)(mkbits >> (kt * 4));
#pragma unroll
        for (int sub = 0; sub < 4; ++sub) {
            v8s bk0 = *reinterpret_cast<const v8s*>(&kbase[(sub * 16 + lc) * HD + lg * 8]);
            v8s bk1 = *reinterpret_cast<const v8s*>(&kbase[(sub * 16 + lc) * HD + 32 + lg * 8]);
            v4f c4 = {0.f, 0.f, 0.f, 0.f};
            c4 = __builtin_amdgcn_mfma_f32_16x16x32_bf16(aq0, bk0, c4, 0, 0, 0);
            c4 = __builtin_amdgcn_mfma_f32_16x16x32_bf16(aq1, bk1, c4, 0, 0, 0);
            int kg = kt * 64 + sub * 16 + lc;
            const bool mk = (nib >> sub) & 1;
#pragma unroll
            for (int r = 0; r < 4; ++r) {
                int lq = wq + lg * 4 + r;
                int dlt = kg - (qbase + lq);
                bool inband = dorel && (dlt > -RR) && (dlt < RR);
                float val = c4[r];
                if (dorel) {
                    float relv;
                    if (inband) relv = b2f(qrel[lq][dlt + RR]);
                    else        relv = (dlt <= -RR) ? relL[r] : relR[r];
                    val += relv;
                }
                if (mk) val = NEGINF;
                float p = __expf(val) * invl[r];
                arow[(size_t)lq * SS + kg] = p;
                Plds[lq][sub * 16 + lc] = f2b(p);
                if (inband) wbin[lq][dlt + RR] = f2b(p);
                else if (dorel) {
                    if (dlt <= -RR) e0l[r] += p;
                    else            e1l[r] += p;
                }
            }
        }
        // PV for this tile (A from own Plds rows, B = V^T frags from global)
        v8s ap0 = *reinterpret_cast<const v8s*>(&Plds[wq + lc][lg * 8]);
        v8s ap1 = *reinterpret_cast<const v8s*>(&Plds[wq + lc][32 + lg * 8]);
        const ushort* vbase = vtb + bhoff + kt * 64;
#pragma unroll
        for (int dt = 0; dt < 4; ++dt) {
            v8s bv0 = *reinterpret_cast<const v8s*>(&vbase[(size_t)(dt * 16 + lc) * SS + lg * 8]);
            v8s bv1 = *reinterpret_cast<const v8s*>(&vbase[(size_t)(dt * 16 + lc) * SS + 32 + lg * 8]);
            o[dt] = __builtin_amdgcn_mfma_f32_16x16x32_bf16(ap0, bv0, o[dt], 0, 0, 0);
            o[dt] = __builtin_amdgcn_mfma_f32_16x16x32_bf16(ap1, bv1, o[dt], 0, 0, 0);
        }
    }

    // edge-bin reduce (over the 16 col-lanes) + write; e1 kept for stok fixup
    float e1s[4];
#pragma unroll
    for (int r = 0; r < 4; ++r) {
        float s0 = e0l[r], s1 = e1l[r];
        s0 += __shfl_xor(s0, 1); s0 += __shfl_xor(s0, 2);
        s0 += __shfl_xor(s0, 4); s0 += __shfl_xor(s0, 8);
        s1 += __shfl_xor(s1, 1); s1 += __shfl_xor(s1, 2);
        s1 += __shfl_xor(s1, 4); s1 += __shfl_xor(s1, 8);
        e1s[r] = s1;
        if (lc == 0) {
            wbin[wq + lg * 4 + r][0] = f2b(s0);
            if (qstm) wbin[wq + lg * 4 + r][32] = f2b(s1);
        }
    }

    // ---- rel-v virtual tile: stage relv^T into Plds (cross-wave) ----
    __syncthreads();
    {
        const float* tabv = qstm ? smv : relv;
        for (int idx = t; idx < 64 * 64; idx += 128) {
            int d = idx >> 6, v = idx & 63;
            float f = (v < NV) ? tabv[(size_t)v * HD + d] : 0.f;
            Plds[d][v] = f2b(f);
        }
    }
    __syncthreads();
    {
        v8s aw0 = *reinterpret_cast<const v8s*>(&wbin[wq + lc][lg * 8]);
        v8s aw1 = *reinterpret_cast<const v8s*>(&wbin[wq + lc][32 + lg * 8]);
#pragma unroll
        for (int dt = 0; dt < 4; ++dt) {
            v8s bv0 = *reinterpret_cast<const v8s*>(&Plds[dt * 16 + lc][lg * 8]);
            v8s bv1 = *reinterpret_cast<const v8s*>(&Plds[dt * 16 + lc][32 + lg * 8]);
            o[dt] = __builtin_amdgcn_mfma_f32_16x16x32_bf16(aw0, bv0, o[dt], 0, 0, 0);
            o[dt] = __builtin_amdgcn_mfma_f32_16x16x32_bf16(aw1, bv1, o[dt], 0, 0, 0);
        }
        if (!qstm) {   // rank-1 fixup for bin v=64 (register-local: rows match)
#pragma unroll
            for (int dt = 0; dt < 4; ++dt)
#pragma unroll
                for (int r = 0; r < 4; ++r)
                    o[dt][r] += e1s[r] * relv[(size_t)64 * HD + dt * 16 + lc];
        }
    }

    // write ctx as bf16 hi/lo [b][s][h*64+d]
#pragma unroll
    for (int dt = 0; dt < 4; ++dt)
#pragma unroll
        for (int r = 0; r < 4; ++r) {
            int gq = qbase + wq + lg * 4 + r;
            size_t idx = ((size_t)b * SS + gq) * DIM + h * HD + dt * 16 + lc;
            float v = o[dt][r];
            ushort hi = f2b(v);
            ctxh[idx] = hi;
            ctxl[idx] = f2b(v - b2f(hi));
        }
}

// ---------------------------------------------------------------------------
extern "C" void kernel_launch(void* const* d_in, const int* in_sizes, int n_in,
                              void* d_out, int out_size, void* d_ws, size_t ws_size,
                              hipStream_t stream)
{
    const float*   stok  = (const float*)d_in[0];
    const float*   stm   = (const float*)d_in[1];
    const uint8_t* mtok  = (const uint8_t*)d_in[2];
    const uint8_t* mstm  = (const uint8_t*)d_in[3];
    const float*   qkv_w = (const float*)d_in[4];
    const float*   qkv_b = (const float*)d_in[5];
    const float*   out_w = (const float*)d_in[6];
    const float*   out_b = (const float*)d_in[7];
    const float*   relk  = (const float*)d_in[8];
    const float*   relv  = (const float*)d_in[9];
    const float*   smk   = (const float*)d_in[10];
    const float*   smv   = (const float*)d_in[11];

    float* out_final = (float*)d_out;
    float* out_attn  = out_final + (size_t)BB * SS * DIM;

    const size_t SZ = (size_t)BB * HH * SS * HD;           // 5,242,880
    ushort* qb16 = (ushort*)d_ws;
    ushort* kb16 = qb16 + SZ;
    ushort* vt16 = kb16 + SZ;
    ushort* xb16 = vt16 + SZ;                              // 5,242,880 ushorts
    ushort* wb16 = xb16 + SZ;                              // 3,145,728 ushorts
    ushort* ctxh = wb16 + (size_t)3 * DIM * DIM;
    ushort* ctxl = ctxh + SZ;
    ushort* woh  = ctxl + SZ;                              // 1,048,576 ushorts
    ushort* wol  = woh + (size_t)DIM * DIM;

    cvt_bf16<<<dim3(9216), dim3(256), 0, stream>>>(stok, stm, qkv_w, out_w,
                                                   xb16, wb16, woh, wol);
    gemm_qkv_mfma<<<dim3(960), dim3(256), 0, stream>>>(xb16, wb16, qkv_b, qb16, kb16, vt16);
    attn_mfma<<<dim3(2560), dim3(128), 0, stream>>>(qb16, kb16, vt16, mtok, mstm,
                                                    relk, relv, smk, smv, out_attn, ctxh, ctxl);
    gemm_out_mfma<<<dim3(640), dim3(256), 0, stream>>>(ctxh, ctxl, woh, wol, out_b, out_final);
}

// Round 11
// 445.730 us; speedup vs baseline: 1.0273x; 1.0273x over previous
//
#include <hip/hip_runtime.h>
#include <stdint.h>

// Problem constants
#define BB    8
#define HH    16
#define SS    640
#define STOK  512
#define STMN  128
#define HD    64
#define DIM   1024
#define NEGINF (-1e18f)

typedef short v8s __attribute__((ext_vector_type(8)));
typedef float v4f __attribute__((ext_vector_type(4)));

static __device__ __forceinline__ ushort f2b(float f) {
    union { float f; uint32_t u; } x; x.f = f;
    uint32_t u = (x.u + 0x7FFFu + ((x.u >> 16) & 1u)) >> 16;
    return (ushort)u;
}
static __device__ __forceinline__ float b2f(ushort h) {
    union { uint32_t u; float f; } x; x.u = ((uint32_t)h) << 16;
    return x.f;
}

// ---------------------------------------------------------------------------
// Kernel A0: convert x (stok||stm, [5120][1024]) and qkv_w ([3072][1024]) to
// bf16; split out_w ([1024][1024]) into bf16 hi/lo pair.  Pure streaming.
// ---------------------------------------------------------------------------
__global__ __launch_bounds__(256) void cvt_bf16(
    const float* __restrict__ stok, const float* __restrict__ stm,
    const float* __restrict__ W, const float* __restrict__ Wo,
    ushort* __restrict__ xb, ushort* __restrict__ Wb,
    ushort* __restrict__ Woh, ushort* __restrict__ Wol)
{
    const int i = blockIdx.x * 256 + threadIdx.x;
    const int XG = 5120 * 256;                      // float4-groups in x
    const int WG = 3072 * 256;                      // float4-groups in qkv_w
    if (i < XG + WG) {
        float4 v; ushort* dst;
        if (i < XG) {
            int row = i >> 8, g = i & 255;
            int b = row / SS, s = row % SS;
            const float* src = (s < STOK)
                ? stok + ((size_t)b * STOK + s) * DIM
                : stm  + ((size_t)b * STMN + (s - STOK)) * DIM;
            v = *reinterpret_cast<const float4*>(src + g * 4);
            dst = xb + (size_t)row * DIM + g * 4;
        } else {
            int j = i - XG;
            int row = j >> 8, g = j & 255;
            v = *reinterpret_cast<const float4*>(W + (size_t)row * DIM + g * 4);
            dst = Wb + (size_t)row * DIM + g * 4;
        }
        ushort4 o;
        o.x = f2b(v.x); o.y = f2b(v.y); o.z = f2b(v.z); o.w = f2b(v.w);
        *reinterpret_cast<ushort4*>(dst) = o;
    } else {
        int j = i - XG - WG;
        int row = j >> 8, g = j & 255;
        float4 v = *reinterpret_cast<const float4*>(Wo + (size_t)row * DIM + g * 4);
        ushort4 hi, lo;
        hi.x = f2b(v.x); lo.x = f2b(v.x - b2f(hi.x));
        hi.y = f2b(v.y); lo.y = f2b(v.y - b2f(hi.y));
        hi.z = f2b(v.z); lo.z = f2b(v.z - b2f(hi.z));
        hi.w = f2b(v.w); lo.w = f2b(v.w - b2f(hi.w));
        *reinterpret_cast<ushort4*>(&Woh[(size_t)row * DIM + g * 4]) = hi;
        *reinterpret_cast<ushort4*>(&Wol[(size_t)row * DIM + g * 4]) = lo;
    }
}

// ---------------------------------------------------------------------------
// Kernel A: QKV projection via MFMA, barrier-free direct-global fragments.
// Block = 128x128 output tile; 4 waves (2x2), each 64x64 = 4x4 fragments.
// Epilogue: bf16 q[bh][s][d] (pre-scaled 1/8), k[bh][s][d], vT[bh][d][s].
// ---------------------------------------------------------------------------
__global__ __launch_bounds__(256, 4) void gemm_qkv_mfma(
    const ushort* __restrict__ xb, const ushort* __restrict__ Wb,
    const float* __restrict__ bias,
    ushort* __restrict__ qb, ushort* __restrict__ kb, ushort* __restrict__ vtb)
{
    const int t = threadIdx.x, lane = t & 63, w = t >> 6;
    const int swz = ((blockIdx.x & 7) * 120) + (blockIdx.x >> 3);
    const int nt = swz / 40, mt = swz % 40;
    const int mb = mt * 128, nb = nt * 128;
    const int wm = (w >> 1) * 64, wn = (w & 1) * 64;
    const int lg = lane >> 4, lc = lane & 15;

    const ushort* pA[4];
    const ushort* pB[4];
#pragma unroll
    for (int i = 0; i < 4; ++i) {
        pA[i] = xb + (size_t)(mb + wm + i * 16 + lc) * DIM + lg * 8;
        pB[i] = Wb + (size_t)(nb + wn + i * 16 + lc) * DIM + lg * 8;
    }

    v4f acc[4][4];
#pragma unroll
    for (int i = 0; i < 4; ++i)
#pragma unroll
        for (int j = 0; j < 4; ++j) acc[i][j] = (v4f){0.f, 0.f, 0.f, 0.f};

#pragma unroll 2
    for (int kt = 0; kt < 32; ++kt) {
        const int ko = kt * 32;
        v8s af[4], bf[4];
#pragma unroll
        for (int i = 0; i < 4; ++i) af[i] = *reinterpret_cast<const v8s*>(pA[i] + ko);
#pragma unroll
        for (int i = 0; i < 4; ++i) bf[i] = *reinterpret_cast<const v8s*>(pB[i] + ko);
#pragma unroll
        for (int i = 0; i < 4; ++i)
#pragma unroll
            for (int j = 0; j < 4; ++j)
                acc[i][j] = __builtin_amdgcn_mfma_f32_16x16x32_bf16(af[i], bf[j], acc[i][j], 0, 0, 0);
    }

    const int nregion = nb >> 10;                  // 0=q 1=k 2=v (tile within one region)
    if (nregion < 2) {
        ushort* dst = nregion ? kb : qb;
        const float scale = nregion ? 1.0f : 0.125f;
#pragma unroll
        for (int j = 0; j < 4; ++j) {
            int n = nb + wn + j * 16 + lc;
            int nn = n & 1023, h = nn >> 6, d = nn & 63;
            float bi = bias[n];
#pragma unroll
            for (int i = 0; i < 4; ++i) {
                int m0 = mb + wm + i * 16 + lg * 4;
                int b = m0 / SS, s0 = m0 % SS;
                size_t base = (((size_t)b * HH + h) * SS + s0) * HD + d;
#pragma unroll
                for (int r = 0; r < 4; ++r)
                    dst[base + (size_t)r * HD] = f2b((acc[i][j][r] + bi) * scale);
            }
        }
    } else {
#pragma unroll
        for (int j = 0; j < 4; ++j) {
            int n = nb + wn + j * 16 + lc;
            int nn = n & 1023, h = nn >> 6, d = nn & 63;
            float bi = bias[n];
#pragma unroll
            for (int i = 0; i < 4; ++i) {
                int m0 = mb + wm + i * 16 + lg * 4;   // 4 consecutive s, same b
                int b = m0 / SS, s0 = m0 % SS;
                ushort4 pk;
                pk.x = f2b(acc[i][j][0] + bi);
                pk.y = f2b(acc[i][j][1] + bi);
                pk.z = f2b(acc[i][j][2] + bi);
                pk.w = f2b(acc[i][j][3] + bi);
                *reinterpret_cast<ushort4*>(
                    &vtb[(((size_t)b * HH + h) * HD + d) * SS + s0]) = pk;
            }
        }
    }
}

// ---------------------------------------------------------------------------
// Kernel C: out projection via MFMA, double-bf16 (hi/lo), fused passes:
// per K-step load ah/al/bh/bl and fire 24 MFMAs (hh, lh, hl) -> 3x ILP.
// m-major XCD swizzle: each XCD owns 1/8 of ctx rows, re-reads only W (4MB).
// Block = 64x128 tile (640 blocks); 4 waves 2x2, wave 32x64 = 2x4 frags.
// ---------------------------------------------------------------------------
__global__ __launch_bounds__(256, 4) void gemm_out_mfma(
    const ushort* __restrict__ Xh, const ushort* __restrict__ Xl,
    const ushort* __restrict__ Wh, const ushort* __restrict__ Wl,
    const float* __restrict__ bias, float* __restrict__ out)
{
    const int t = threadIdx.x, lane = t & 63, w = t >> 6;
    // m-major: XCD k owns swz in [80k, 80k+80) -> mt in [10k,10k+10), all nt
    const int swz = ((blockIdx.x & 7) * 80) + (blockIdx.x >> 3);
    const int mt = swz >> 3, nt = swz & 7;
    const int mb = mt * 64, nb = nt * 128;
    const int wm = (w >> 1) * 32, wn = (w & 1) * 64;
    const int lg = lane >> 4, lc = lane & 15;

    size_t aoff[2];
    size_t boff[4];
#pragma unroll
    for (int i = 0; i < 2; ++i)
        aoff[i] = (size_t)(mb + wm + i * 16 + lc) * DIM + lg * 8;
#pragma unroll
    for (int j = 0; j < 4; ++j)
        boff[j] = (size_t)(nb + wn + j * 16 + lc) * DIM + lg * 8;

    v4f acc[2][4];
#pragma unroll
    for (int i = 0; i < 2; ++i)
#pragma unroll
        for (int j = 0; j < 4; ++j) acc[i][j] = (v4f){0.f, 0.f, 0.f, 0.f};

#pragma unroll 2
    for (int kt = 0; kt < 32; ++kt) {
        const int ko = kt * 32;
        v8s ah[2], al[2], bh[4], bl[4];
#pragma unroll
        for (int i = 0; i < 2; ++i) {
            ah[i] = *reinterpret_cast<const v8s*>(Xh + aoff[i] + ko);
            al[i] = *reinterpret_cast<const v8s*>(Xl + aoff[i] + ko);
        }
#pragma unroll
        for (int j = 0; j < 4; ++j) {
            bh[j] = *reinterpret_cast<const v8s*>(Wh + boff[j] + ko);
            bl[j] = *reinterpret_cast<const v8s*>(Wl + boff[j] + ko);
        }
#pragma unroll
        for (int i = 0; i < 2; ++i)
#pragma unroll
            for (int j = 0; j < 4; ++j)
                acc[i][j] = __builtin_amdgcn_mfma_f32_16x16x32_bf16(ah[i], bh[j], acc[i][j], 0, 0, 0);
#pragma unroll
        for (int i = 0; i < 2; ++i)
#pragma unroll
            for (int j = 0; j < 4; ++j)
                acc[i][j] = __builtin_amdgcn_mfma_f32_16x16x32_bf16(al[i], bh[j], acc[i][j], 0, 0, 0);
#pragma unroll
        for (int i = 0; i < 2; ++i)
#pragma unroll
            for (int j = 0; j < 4; ++j)
                acc[i][j] = __builtin_amdgcn_mfma_f32_16x16x32_bf16(ah[i], bl[j], acc[i][j], 0, 0, 0);
    }

#pragma unroll
    for (int j = 0; j < 4; ++j) {
        int n = nb + wn + j * 16 + lc;
        float bi = bias[n];
#pragma unroll
        for (int i = 0; i < 2; ++i) {
            int m0 = mb + wm + i * 16 + lg * 4;
#pragma unroll
            for (int r = 0; r < 4; ++r)
                out[(size_t)(m0 + r) * DIM + n] = acc[i][j][r] + bi;
        }
    }
}

// ---------------------------------------------------------------------------
// Kernel B: barrier-free MFMA attention with DENSE cooperative attn writes.
// Block = 128 threads (2 waves) x 32 q-rows; grid 2560 (= 2 exact rounds at
// 5 blocks/CU).  Sweep-2 stages each tile's probs in a per-wave f32 LDS
// buffer (Pf), then writes them back as 4x float4 per lane with each
// 16-lane group covering 256 B contiguous -> store ops/tile drop 16->4 and
// all segments are dense (the old 16 scalar scattered stores serialized
// every tile through the vmcnt FIFO).
// ---------------------------------------------------------------------------
__global__ __launch_bounds__(128, 6) void attn_mfma(
    const ushort* __restrict__ qb, const ushort* __restrict__ kb,
    const ushort* __restrict__ vtb,
    const uint8_t* __restrict__ mtok, const uint8_t* __restrict__ mstm,
    const float* __restrict__ relk, const float* __restrict__ relv,
    const float* __restrict__ smk,  const float* __restrict__ smv,
    float* __restrict__ attn_out,
    ushort* __restrict__ ctxh, ushort* __restrict__ ctxl)
{
    __shared__ ushort qrel[32][72];
    __shared__ ushort Plds[64][72];    // rows 0..31: P; all 64 rows: relv^T
    __shared__ ushort wbin[32][72];
    __shared__ float  Pf[32][68];      // per-tile f32 probs staging

    const int t    = threadIdx.x;
    const int lane = t & 63, w = t >> 6;
    const int swz  = ((blockIdx.x & 7) * 320) + (blockIdx.x >> 3);  // XCD-contiguous
    const int qt = swz % 20, bh = swz / 20;
    const int b = bh >> 4, h = bh & 15;
    const int qbase = qt * 32;
    const bool qstm = (qt >= 16);
    const size_t bhoff = (size_t)bh * (SS * HD);
    const int wq = w * 16, lg = lane >> 4, lc = lane & 15;
    const int RR = qstm ? 16 : 32;
    const int NV = qstm ? 33 : 65;
    const float* tabk = qstm ? smk : relk;

    // zero this wave's wbin rows (own rows only -> no barrier needed)
    for (int i = lane; i < 16 * 36; i += 64) {
        int r = i / 36, c = i - r * 36;
        *reinterpret_cast<uint32_t*>(&wbin[wq + r][c * 2]) = 0u;
    }

    // stm blocks: zero attn cols 0..511 (scores are -inf there)
    if (qstm) {
        float4 z = make_float4(0.f, 0.f, 0.f, 0.f);
        float* dst = attn_out + ((size_t)bh * SS + qbase) * SS;
        for (int idx = t; idx < 32 * 128; idx += 128) {
            int r = idx >> 7, c4 = idx & 127;
            *reinterpret_cast<float4*>(&dst[(size_t)r * SS + c4 * 4]) = z;
        }
    }

    // per-lane pad-mask bitmask: bit kt*4+sub covers key kg = kt*64+sub*16+lc
    uint64_t mkbits = 0;
#pragma unroll
    for (int kt = 0; kt < 10; ++kt)
#pragma unroll
        for (int sub = 0; sub < 4; ++sub) {
            int kg = kt * 64 + sub * 16 + lc;
            uint8_t m = (kg < STOK) ? mtok[b * STOK + kg] : mstm[b * STMN + kg - STOK];
            mkbits |= ((uint64_t)(m ? 1u : 0u)) << (kt * 4 + sub);
        }

    // Q A-fragments straight from global (row = qbase+wq+lc)
    const int qrow = qbase + wq + lc;
    v8s aq0 = *reinterpret_cast<const v8s*>(&qb[bhoff + (size_t)qrow * HD + lg * 8]);
    v8s aq1 = *reinterpret_cast<const v8s*>(&qb[bhoff + (size_t)qrow * HD + 32 + lg * 8]);

    // qrel[i][v] = q_i . rel_emb_k[v] via MFMA (wave's own 16 rows)
    {
        const int ndt = qstm ? 2 : 4;
        for (int dt = 0; dt < ndt; ++dt) {
            const float* rp = tabk + (size_t)(dt * 16 + lc) * HD;
            v8s bk0, bk1;
#pragma unroll
            for (int j = 0; j < 8; ++j) {
                bk0[j] = (short)f2b(rp[lg * 8 + j]);
                bk1[j] = (short)f2b(rp[32 + lg * 8 + j]);
            }
            v4f c4 = {0.f, 0.f, 0.f, 0.f};
            c4 = __builtin_amdgcn_mfma_f32_16x16x32_bf16(aq0, bk0, c4, 0, 0, 0);
            c4 = __builtin_amdgcn_mfma_f32_16x16x32_bf16(aq1, bk1, c4, 0, 0, 0);
#pragma unroll
            for (int r = 0; r < 4; ++r)
                qrel[wq + lg * 4 + r][dt * 16 + lc] = f2b(c4[r]);
        }
        // last column v = NV-1 (row NV-1 of table), scalar partial + shfl
        const float* rp = tabk + (size_t)(NV - 1) * HD;
        float part = 0.f;
#pragma unroll
        for (int j = 0; j < 8; ++j) {
            part += b2f((ushort)aq0[j]) * rp[lg * 8 + j];
            part += b2f((ushort)aq1[j]) * rp[32 + lg * 8 + j];
        }
        part += __shfl_xor(part, 16);
        part += __shfl_xor(part, 32);
        if (lg == 0) qrel[wq + lc][NV - 1] = f2b(part);
    }

    // register-cached saturated rel values (clamp hits these for ~85% of keys)
    float relL[4], relR[4];
#pragma unroll
    for (int r = 0; r < 4; ++r) {
        int lq = wq + lg * 4 + r;
        relL[r] = b2f(qrel[lq][0]);
        relR[r] = b2f(qrel[lq][2 * RR]);
    }

    const int tile0 = qstm ? 8 : 0;
    float lsum[4] = {0.f, 0.f, 0.f, 0.f};

    // ---- sweep 1: exp-sums (K-frags from global, no barriers) ----
    for (int kt = tile0; kt < 10; ++kt) {
        const ushort* kbase = kb + bhoff + (size_t)(kt * 64) * HD;
        const bool dorel = qstm || (kt < 8);
        const uint32_t nib = (uint32_t)(mkbits >> (kt * 4));
#pragma unroll
        for (int sub = 0; sub < 4; ++sub) {
            v8s bk0 = *reinterpret_cast<const v8s*>(&kbase[(sub * 16 + lc) * HD + lg * 8]);
            v8s bk1 = *reinterpret_cast<const v8s*>(&kbase[(sub * 16 + lc) * HD + 32 + lg * 8]);
            v4f c4 = {0.f, 0.f, 0.f, 0.f};
            c4 = __builtin_amdgcn_mfma_f32_16x16x32_bf16(aq0, bk0, c4, 0, 0, 0);
            c4 = __builtin_amdgcn_mfma_f32_16x16x32_bf16(aq1, bk1, c4, 0, 0, 0);
            int kg = kt * 64 + sub * 16 + lc;
            const bool mk = (nib >> sub) & 1;
#pragma unroll
            for (int r = 0; r < 4; ++r) {
                int lq = wq + lg * 4 + r;
                float val = c4[r];
                if (dorel) {
                    int dlt = kg - (qbase + lq);
                    float relv;
                    if (dlt > -RR && dlt < RR)
                        relv = b2f(qrel[lq][dlt + RR]);     // band only
                    else
                        relv = (dlt <= -RR) ? relL[r] : relR[r];
                    val += relv;
                }
                if (mk) val = NEGINF;
                lsum[r] += __expf(val);
            }
        }
    }

    float invl[4];
#pragma unroll
    for (int r = 0; r < 4; ++r) {
        float s = lsum[r];
        s += __shfl_xor(s, 1); s += __shfl_xor(s, 2);
        s += __shfl_xor(s, 4); s += __shfl_xor(s, 8);
        invl[r] = 1.f / s;
    }

    v4f o[4];
#pragma unroll
    for (int dt = 0; dt < 4; ++dt) o[dt] = (v4f){0.f, 0.f, 0.f, 0.f};
    float e0l[4] = {0.f, 0.f, 0.f, 0.f};
    float e1l[4] = {0.f, 0.f, 0.f, 0.f};
    float* arow = attn_out + ((size_t)bh * SS + qbase) * SS;

    // ---- sweep 2: probs -> Pf/Plds/wbin, PV, then dense attn store ----
    for (int kt = tile0; kt < 10; ++kt) {
        const ushort* kbase = kb + bhoff + (size_t)(kt * 64) * HD;
        const bool dorel = qstm || (kt < 8);
        const uint32_t nib = (uint32_t)(mkbits >> (kt * 4));
#pragma unroll
        for (int sub = 0; sub < 4; ++sub) {
            v8s bk0 = *reinterpret_cast<const v8s*>(&kbase[(sub * 16 + lc) * HD + lg * 8]);
            v8s bk1 = *reinterpret_cast<const v8s*>(&kbase[(sub * 16 + lc) * HD + 32 + lg * 8]);
            v4f c4 = {0.f, 0.f, 0.f, 0.f};
            c4 = __builtin_amdgcn_mfma_f32_16x16x32_bf16(aq0, bk0, c4, 0, 0, 0);
            c4 = __builtin_amdgcn_mfma_f32_16x16x32_bf16(aq1, bk1, c4, 0, 0, 0);
            int kg = kt * 64 + sub * 16 + lc;
            const bool mk = (nib >> sub) & 1;
#pragma unroll
            for (int r = 0; r < 4; ++r) {
                int lq = wq + lg * 4 + r;
                int dlt = kg - (qbase + lq);
                bool inband = dorel && (dlt > -RR) && (dlt < RR);
                float val = c4[r];
                if (dorel) {
                    float relv;
                    if (inband) relv = b2f(qrel[lq][dlt + RR]);
                    else        relv = (dlt <= -RR) ? relL[r] : relR[r];
                    val += relv;
                }
                if (mk) val = NEGINF;
                float p = __expf(val) * invl[r];
                Pf[lq][sub * 16 + lc] = p;          // f32 staging (LDS, own rows)
                Plds[lq][sub * 16 + lc] = f2b(p);
                if (inband) wbin[lq][dlt + RR] = f2b(p);
                else if (dorel) {
                    if (dlt <= -RR) e0l[r] += p;
                    else            e1l[r] += p;
                }
            }
        }
        // PV for this tile (A from own Plds rows, B = V^T frags from global)
        v8s ap0 = *reinterpret_cast<const v8s*>(&Plds[wq + lc][lg * 8]);
        v8s ap1 = *reinterpret_cast<const v8s*>(&Plds[wq + lc][32 + lg * 8]);
        const ushort* vbase = vtb + bhoff + kt * 64;
#pragma unroll
        for (int dt = 0; dt < 4; ++dt) {
            v8s bv0 = *reinterpret_cast<const v8s*>(&vbase[(size_t)(dt * 16 + lc) * SS + lg * 8]);
            v8s bv1 = *reinterpret_cast<const v8s*>(&vbase[(size_t)(dt * 16 + lc) * SS + 32 + lg * 8]);
            o[dt] = __builtin_amdgcn_mfma_f32_16x16x32_bf16(ap0, bv0, o[dt], 0, 0, 0);
            o[dt] = __builtin_amdgcn_mfma_f32_16x16x32_bf16(ap1, bv1, o[dt], 0, 0, 0);
        }
        // dense attn write: wave reads back its own 16 Pf rows; each 16-lane
        // group stores 256 B contiguous (row = wq + rr*4 + lg, cols lc*4..+4)
        {
            const int kb2 = kt * 64;
#pragma unroll
            for (int rr = 0; rr < 4; ++rr) {
                int row = wq + rr * 4 + lg;
                float4 pv4 = *reinterpret_cast<float4*>(&Pf[row][lc * 4]);
                *reinterpret_cast<float4*>(&arow[(size_t)row * SS + kb2 + lc * 4]) = pv4;
            }
        }
    }

    // edge-bin reduce (over the 16 col-lanes) + write; e1 kept for stok fixup
    float e1s[4];
#pragma unroll
    for (int r = 0; r < 4; ++r) {
        float s0 = e0l[r], s1 = e1l[r];
        s0 += __shfl_xor(s0, 1); s0 += __shfl_xor(s0, 2);
        s0 += __shfl_xor(s0, 4); s0 += __shfl_xor(s0, 8);
        s1 += __shfl_xor(s1, 1); s1 += __shfl_xor(s1, 2);
        s1 += __shfl_xor(s1, 4); s1 += __shfl_xor(s1, 8);
        e1s[r] = s1;
        if (lc == 0) {
            wbin[wq + lg * 4 + r][0] = f2b(s0);
            if (qstm) wbin[wq + lg * 4 + r][32] = f2b(s1);
        }
    }

    // ---- rel-v virtual tile: stage relv^T into Plds (cross-wave) ----
    __syncthreads();
    {
        const float* tabv = qstm ? smv : relv;
        for (int idx = t; idx < 64 * 64; idx += 128) {
            int d = idx >> 6, v = idx & 63;
            float f = (v < NV) ? tabv[(size_t)v * HD + d] : 0.f;
            Plds[d][v] = f2b(f);
        }
    }
    __syncthreads();
    {
        v8s aw0 = *reinterpret_cast<const v8s*>(&wbin[wq + lc][lg * 8]);
        v8s aw1 = *reinterpret_cast<const v8s*>(&wbin[wq + lc][32 + lg * 8]);
#pragma unroll
        for (int dt = 0; dt < 4; ++dt) {
            v8s bv0 = *reinterpret_cast<const v8s*>(&Plds[dt * 16 + lc][lg * 8]);
            v8s bv1 = *reinterpret_cast<const v8s*>(&Plds[dt * 16 + lc][32 + lg * 8]);
            o[dt] = __builtin_amdgcn_mfma_f32_16x16x32_bf16(aw0, bv0, o[dt], 0, 0, 0);
            o[dt] = __builtin_amdgcn_mfma_f32_16x16x32_bf16(aw1, bv1, o[dt], 0, 0, 0);
        }
        if (!qstm) {   // rank-1 fixup for bin v=64 (register-local: rows match)
#pragma unroll
            for (int dt = 0; dt < 4; ++dt)
#pragma unroll
                for (int r = 0; r < 4; ++r)
                    o[dt][r] += e1s[r] * relv[(size_t)64 * HD + dt * 16 + lc];
        }
    }

    // write ctx as bf16 hi/lo [b][s][h*64+d]
#pragma unroll
    for (int dt = 0; dt < 4; ++dt)
#pragma unroll
        for (int r = 0; r < 4; ++r) {
            int gq = qbase + wq + lg * 4 + r;
            size_t idx = ((size_t)b * SS + gq) * DIM + h * HD + dt * 16 + lc;
            float v = o[dt][r];
            ushort hi = f2b(v);
            ctxh[idx] = hi;
            ctxl[idx] = f2b(v - b2f(hi));
        }
}

// ---------------------------------------------------------------------------
extern "C" void kernel_launch(void* const* d_in, const int* in_sizes, int n_in,
                              void* d_out, int out_size, void* d_ws, size_t ws_size,
                              hipStream_t stream)
{
    const float*   stok  = (const float*)d_in[0];
    const float*   stm   = (const float*)d_in[1];
    const uint8_t* mtok  = (const uint8_t*)d_in[2];
    const uint8_t* mstm  = (const uint8_t*)d_in[3];
    const float*   qkv_w = (const float*)d_in[4];
    const float*   qkv_b = (const float*)d_in[5];
    const float*   out_w = (const float*)d_in[6];
    const float*   out_b = (const float*)d_in[7];
    const float*   relk  = (const float*)d_in[8];
    const float*   relv  = (const float*)d_in[9];
    const float*   smk   = (const float*)d_in[10];
    const float*   smv   = (const float*)d_in[11];

    float* out_final = (float*)d_out;
    float* out_attn  = out_final + (size_t)BB * SS * DIM;

    const size_t SZ = (size_t)BB * HH * SS * HD;           // 5,242,880
    ushort* qb16 = (ushort*)d_ws;
    ushort* kb16 = qb16 + SZ;
    ushort* vt16 = kb16 + SZ;
    ushort* xb16 = vt16 + SZ;                              // 5,242,880 ushorts
    ushort* wb16 = xb16 + SZ;                              // 3,145,728 ushorts
    ushort* ctxh = wb16 + (size_t)3 * DIM * DIM;
    ushort* ctxl = ctxh + SZ;
    ushort* woh  = ctxl + SZ;                              // 1,048,576 ushorts
    ushort* wol  = woh + (size_t)DIM * DIM;

    cvt_bf16<<<dim3(9216), dim3(256), 0, stream>>>(stok, stm, qkv_w, out_w,
                                                   xb16, wb16, woh, wol);
    gemm_qkv_mfma<<<dim3(960), dim3(256), 0, stream>>>(xb16, wb16, qkv_b, qb16, kb16, vt16);
    attn_mfma<<<dim3(2560), dim3(128), 0, stream>>>(qb16, kb16, vt16, mtok, mstm,
                                                    relk, relv, smk, smv, out_attn, ctxh, ctxl);
    gemm_out_mfma<<<dim3(640), dim3(256), 0, stream>>>(ctxh, ctxl, woh, wol, out_b, out_final);
}

// Round 12
// 439.375 us; speedup vs baseline: 1.0422x; 1.0145x over previous
//
#include <hip/hip_runtime.h>
#include <stdint.h>

// Problem constants
#define BB    8
#define HH    16
#define SS    640
#define STOK  512
#define STMN  128
#define HD    64
#define DIM   1024
#define NEGINF (-1e18f)

typedef short v8s __attribute__((ext_vector_type(8)));
typedef float v4f __attribute__((ext_vector_type(4)));

static __device__ __forceinline__ ushort f2b(float f) {
    union { float f; uint32_t u; } x; x.f = f;
    uint32_t u = (x.u + 0x7FFFu + ((x.u >> 16) & 1u)) >> 16;
    return (ushort)u;
}
static __device__ __forceinline__ float b2f(ushort h) {
    union { uint32_t u; float f; } x; x.u = ((uint32_t)h) << 16;
    return x.f;
}

// ---------------------------------------------------------------------------
// Kernel A0: convert x (stok||stm, [5120][1024]) and qkv_w ([3072][1024]) to
// bf16; split out_w ([1024][1024]) into bf16 hi/lo pair.  Pure streaming.
// ---------------------------------------------------------------------------
__global__ __launch_bounds__(256) void cvt_bf16(
    const float* __restrict__ stok, const float* __restrict__ stm,
    const float* __restrict__ W, const float* __restrict__ Wo,
    ushort* __restrict__ xb, ushort* __restrict__ Wb,
    ushort* __restrict__ Woh, ushort* __restrict__ Wol)
{
    const int i = blockIdx.x * 256 + threadIdx.x;
    const int XG = 5120 * 256;                      // float4-groups in x
    const int WG = 3072 * 256;                      // float4-groups in qkv_w
    if (i < XG + WG) {
        float4 v; ushort* dst;
        if (i < XG) {
            int row = i >> 8, g = i & 255;
            int b = row / SS, s = row % SS;
            const float* src = (s < STOK)
                ? stok + ((size_t)b * STOK + s) * DIM
                : stm  + ((size_t)b * STMN + (s - STOK)) * DIM;
            v = *reinterpret_cast<const float4*>(src + g * 4);
            dst = xb + (size_t)row * DIM + g * 4;
        } else {
            int j = i - XG;
            int row = j >> 8, g = j & 255;
            v = *reinterpret_cast<const float4*>(W + (size_t)row * DIM + g * 4);
            dst = Wb + (size_t)row * DIM + g * 4;
        }
        ushort4 o;
        o.x = f2b(v.x); o.y = f2b(v.y); o.z = f2b(v.z); o.w = f2b(v.w);
        *reinterpret_cast<ushort4*>(dst) = o;
    } else {
        int j = i - XG - WG;
        int row = j >> 8, g = j & 255;
        float4 v = *reinterpret_cast<const float4*>(Wo + (size_t)row * DIM + g * 4);
        ushort4 hi, lo;
        hi.x = f2b(v.x); lo.x = f2b(v.x - b2f(hi.x));
        hi.y = f2b(v.y); lo.y = f2b(v.y - b2f(hi.y));
        hi.z = f2b(v.z); lo.z = f2b(v.z - b2f(hi.z));
        hi.w = f2b(v.w); lo.w = f2b(v.w - b2f(hi.w));
        *reinterpret_cast<ushort4*>(&Woh[(size_t)row * DIM + g * 4]) = hi;
        *reinterpret_cast<ushort4*>(&Wol[(size_t)row * DIM + g * 4]) = lo;
    }
}

// ---------------------------------------------------------------------------
// Kernel A: QKV projection via MFMA, barrier-free direct-global fragments.
// Block = 128x128 output tile; 4 waves (2x2), each 64x64 = 4x4 fragments.
// Epilogue: bf16 q[bh][s][d] (pre-scaled 1/8), k[bh][s][d], vT[bh][d][s].
// ---------------------------------------------------------------------------
__global__ __launch_bounds__(256, 4) void gemm_qkv_mfma(
    const ushort* __restrict__ xb, const ushort* __restrict__ Wb,
    const float* __restrict__ bias,
    ushort* __restrict__ qb, ushort* __restrict__ kb, ushort* __restrict__ vtb)
{
    const int t = threadIdx.x, lane = t & 63, w = t >> 6;
    const int swz = ((blockIdx.x & 7) * 120) + (blockIdx.x >> 3);
    const int nt = swz / 40, mt = swz % 40;
    const int mb = mt * 128, nb = nt * 128;
    const int wm = (w >> 1) * 64, wn = (w & 1) * 64;
    const int lg = lane >> 4, lc = lane & 15;

    const ushort* pA[4];
    const ushort* pB[4];
#pragma unroll
    for (int i = 0; i < 4; ++i) {
        pA[i] = xb + (size_t)(mb + wm + i * 16 + lc) * DIM + lg * 8;
        pB[i] = Wb + (size_t)(nb + wn + i * 16 + lc) * DIM + lg * 8;
    }

    v4f acc[4][4];
#pragma unroll
    for (int i = 0; i < 4; ++i)
#pragma unroll
        for (int j = 0; j < 4; ++j) acc[i][j] = (v4f){0.f, 0.f, 0.f, 0.f};

#pragma unroll 2
    for (int kt = 0; kt < 32; ++kt) {
        const int ko = kt * 32;
        v8s af[4], bf[4];
#pragma unroll
        for (int i = 0; i < 4; ++i) af[i] = *reinterpret_cast<const v8s*>(pA[i] + ko);
#pragma unroll
        for (int i = 0; i < 4; ++i) bf[i] = *reinterpret_cast<const v8s*>(pB[i] + ko);
#pragma unroll
        for (int i = 0; i < 4; ++i)
#pragma unroll
            for (int j = 0; j < 4; ++j)
                acc[i][j] = __builtin_amdgcn_mfma_f32_16x16x32_bf16(af[i], bf[j], acc[i][j], 0, 0, 0);
    }

    const int nregion = nb >> 10;                  // 0=q 1=k 2=v (tile within one region)
    if (nregion < 2) {
        ushort* dst = nregion ? kb : qb;
        const float scale = nregion ? 1.0f : 0.125f;
#pragma unroll
        for (int j = 0; j < 4; ++j) {
            int n = nb + wn + j * 16 + lc;
            int nn = n & 1023, h = nn >> 6, d = nn & 63;
            float bi = bias[n];
#pragma unroll
            for (int i = 0; i < 4; ++i) {
                int m0 = mb + wm + i * 16 + lg * 4;
                int b = m0 / SS, s0 = m0 % SS;
                size_t base = (((size_t)b * HH + h) * SS + s0) * HD + d;
#pragma unroll
                for (int r = 0; r < 4; ++r)
                    dst[base + (size_t)r * HD] = f2b((acc[i][j][r] + bi) * scale);
            }
        }
    } else {
#pragma unroll
        for (int j = 0; j < 4; ++j) {
            int n = nb + wn + j * 16 + lc;
            int nn = n & 1023, h = nn >> 6, d = nn & 63;
            float bi = bias[n];
#pragma unroll
            for (int i = 0; i < 4; ++i) {
                int m0 = mb + wm + i * 16 + lg * 4;   // 4 consecutive s, same b
                int b = m0 / SS, s0 = m0 % SS;
                ushort4 pk;
                pk.x = f2b(acc[i][j][0] + bi);
                pk.y = f2b(acc[i][j][1] + bi);
                pk.z = f2b(acc[i][j][2] + bi);
                pk.w = f2b(acc[i][j][3] + bi);
                *reinterpret_cast<ushort4*>(
                    &vtb[(((size_t)b * HH + h) * HD + d) * SS + s0]) = pk;
            }
        }
    }
}

// ---------------------------------------------------------------------------
// Kernel C: out projection via MFMA, double-bf16 (hi/lo), fused passes:
// per K-step load ah/al/bh/bl and fire 24 MFMAs (hh, lh, hl) -> 3x ILP.
// m-major XCD swizzle: each XCD owns 1/8 of ctx rows, re-reads only W (4MB).
// Block = 64x128 tile (640 blocks); 4 waves 2x2, wave 32x64 = 2x4 frags.
// ---------------------------------------------------------------------------
__global__ __launch_bounds__(256, 4) void gemm_out_mfma(
    const ushort* __restrict__ Xh, const ushort* __restrict__ Xl,
    const ushort* __restrict__ Wh, const ushort* __restrict__ Wl,
    const float* __restrict__ bias, float* __restrict__ out)
{
    const int t = threadIdx.x, lane = t & 63, w = t >> 6;
    // m-major: XCD k owns swz in [80k, 80k+80) -> mt in [10k,10k+10), all nt
    const int swz = ((blockIdx.x & 7) * 80) + (blockIdx.x >> 3);
    const int mt = swz >> 3, nt = swz & 7;
    const int mb = mt * 64, nb = nt * 128;
    const int wm = (w >> 1) * 32, wn = (w & 1) * 64;
    const int lg = lane >> 4, lc = lane & 15;

    size_t aoff[2];
    size_t boff[4];
#pragma unroll
    for (int i = 0; i < 2; ++i)
        aoff[i] = (size_t)(mb + wm + i * 16 + lc) * DIM + lg * 8;
#pragma unroll
    for (int j = 0; j < 4; ++j)
        boff[j] = (size_t)(nb + wn + j * 16 + lc) * DIM + lg * 8;

    v4f acc[2][4];
#pragma unroll
    for (int i = 0; i < 2; ++i)
#pragma unroll
        for (int j = 0; j < 4; ++j) acc[i][j] = (v4f){0.f, 0.f, 0.f, 0.f};

#pragma unroll 2
    for (int kt = 0; kt < 32; ++kt) {
        const int ko = kt * 32;
        v8s ah[2], al[2], bh[4], bl[4];
#pragma unroll
        for (int i = 0; i < 2; ++i) {
            ah[i] = *reinterpret_cast<const v8s*>(Xh + aoff[i] + ko);
            al[i] = *reinterpret_cast<const v8s*>(Xl + aoff[i] + ko);
        }
#pragma unroll
        for (int j = 0; j < 4; ++j) {
            bh[j] = *reinterpret_cast<const v8s*>(Wh + boff[j] + ko);
            bl[j] = *reinterpret_cast<const v8s*>(Wl + boff[j] + ko);
        }
#pragma unroll
        for (int i = 0; i < 2; ++i)
#pragma unroll
            for (int j = 0; j < 4; ++j)
                acc[i][j] = __builtin_amdgcn_mfma_f32_16x16x32_bf16(ah[i], bh[j], acc[i][j], 0, 0, 0);
#pragma unroll
        for (int i = 0; i < 2; ++i)
#pragma unroll
            for (int j = 0; j < 4; ++j)
                acc[i][j] = __builtin_amdgcn_mfma_f32_16x16x32_bf16(al[i], bh[j], acc[i][j], 0, 0, 0);
#pragma unroll
        for (int i = 0; i < 2; ++i)
#pragma unroll
            for (int j = 0; j < 4; ++j)
                acc[i][j] = __builtin_amdgcn_mfma_f32_16x16x32_bf16(ah[i], bl[j], acc[i][j], 0, 0, 0);
    }

#pragma unroll
    for (int j = 0; j < 4; ++j) {
        int n = nb + wn + j * 16 + lc;
        float bi = bias[n];
#pragma unroll
        for (int i = 0; i < 2; ++i) {
            int m0 = mb + wm + i * 16 + lg * 4;
#pragma unroll
            for (int r = 0; r < 4; ++r)
                out[(size_t)(m0 + r) * DIM + n] = acc[i][j][r] + bi;
        }
    }
}

// ---------------------------------------------------------------------------
// Kernel B: SINGLE-PASS barrier-free MFMA attention (deferred normalization).
// Block = 128 threads (2 waves) x 32 q-rows; grid 2560.
// One pass per k-tile: QK^T -> p = exp(val) UNNORMALIZED -> stage bf16 into
// Pfull[32][648] + wbin/e-sums + PV MFMA (unnormalized).  After the loop:
// row-sum -> invl, dense streaming normalize+write of the attn tensor, rel-v
// virtual tile (unnormalized weights), single o*=invl before ctx write.
// Eliminates the entire old sweep-1 (half the QK^T MFMAs / K loads / exp).
// ---------------------------------------------------------------------------
__global__ __launch_bounds__(128) void attn_mfma(
    const ushort* __restrict__ qb, const ushort* __restrict__ kb,
    const ushort* __restrict__ vtb,
    const uint8_t* __restrict__ mtok, const uint8_t* __restrict__ mstm,
    const float* __restrict__ relk, const float* __restrict__ relv,
    const float* __restrict__ smk,  const float* __restrict__ smv,
    float* __restrict__ attn_out,
    ushort* __restrict__ ctxh, ushort* __restrict__ ctxl)
{
    __shared__ ushort qrel[32][72];
    __shared__ ushort Pfull[32][648];   // unnormalized exp(score), bf16
    __shared__ ushort wbin[32][72];
    __shared__ float  linv[32];

    const int t    = threadIdx.x;
    const int lane = t & 63, w = t >> 6;
    const int swz  = ((blockIdx.x & 7) * 320) + (blockIdx.x >> 3);  // XCD-contiguous
    const int qt = swz % 20, bh = swz / 20;
    const int b = bh >> 4, h = bh & 15;
    const int qbase = qt * 32;
    const bool qstm = (qt >= 16);
    const size_t bhoff = (size_t)bh * (SS * HD);
    const int wq = w * 16, lg = lane >> 4, lc = lane & 15;
    const int RR = qstm ? 16 : 32;
    const int NV = qstm ? 33 : 65;
    const float* tabk = qstm ? smk : relk;

    // zero this wave's wbin rows (own rows only -> no barrier needed)
    for (int i = lane; i < 16 * 36; i += 64) {
        int r = i / 36, c = i - r * 36;
        *reinterpret_cast<uint32_t*>(&wbin[wq + r][c * 2]) = 0u;
    }

    // stm blocks: zero attn cols 0..511 (scores are -inf there)
    if (qstm) {
        float4 z = make_float4(0.f, 0.f, 0.f, 0.f);
        float* dst = attn_out + ((size_t)bh * SS + qbase) * SS;
        for (int idx = t; idx < 32 * 128; idx += 128) {
            int r = idx >> 7, c4 = idx & 127;
            *reinterpret_cast<float4*>(&dst[(size_t)r * SS + c4 * 4]) = z;
        }
    }

    // per-lane pad-mask bitmask: bit kt*4+sub covers key kg = kt*64+sub*16+lc
    uint64_t mkbits = 0;
#pragma unroll
    for (int kt = 0; kt < 10; ++kt)
#pragma unroll
        for (int sub = 0; sub < 4; ++sub) {
            int kg = kt * 64 + sub * 16 + lc;
            uint8_t m = (kg < STOK) ? mtok[b * STOK + kg] : mstm[b * STMN + kg - STOK];
            mkbits |= ((uint64_t)(m ? 1u : 0u)) << (kt * 4 + sub);
        }

    // Q A-fragments straight from global (row = qbase+wq+lc)
    const int qrow = qbase + wq + lc;
    v8s aq0 = *reinterpret_cast<const v8s*>(&qb[bhoff + (size_t)qrow * HD + lg * 8]);
    v8s aq1 = *reinterpret_cast<const v8s*>(&qb[bhoff + (size_t)qrow * HD + 32 + lg * 8]);

    // qrel[i][v] = q_i . rel_emb_k[v] via MFMA (wave's own 16 rows)
    {
        const int ndt = qstm ? 2 : 4;
        for (int dt = 0; dt < ndt; ++dt) {
            const float* rp = tabk + (size_t)(dt * 16 + lc) * HD;
            v8s bk0, bk1;
#pragma unroll
            for (int j = 0; j < 8; ++j) {
                bk0[j] = (short)f2b(rp[lg * 8 + j]);
                bk1[j] = (short)f2b(rp[32 + lg * 8 + j]);
            }
            v4f c4 = {0.f, 0.f, 0.f, 0.f};
            c4 = __builtin_amdgcn_mfma_f32_16x16x32_bf16(aq0, bk0, c4, 0, 0, 0);
            c4 = __builtin_amdgcn_mfma_f32_16x16x32_bf16(aq1, bk1, c4, 0, 0, 0);
#pragma unroll
            for (int r = 0; r < 4; ++r)
                qrel[wq + lg * 4 + r][dt * 16 + lc] = f2b(c4[r]);
        }
        // last column v = NV-1 (row NV-1 of table), scalar partial + shfl
        const float* rp = tabk + (size_t)(NV - 1) * HD;
        float part = 0.f;
#pragma unroll
        for (int j = 0; j < 8; ++j) {
            part += b2f((ushort)aq0[j]) * rp[lg * 8 + j];
            part += b2f((ushort)aq1[j]) * rp[32 + lg * 8 + j];
        }
        part += __shfl_xor(part, 16);
        part += __shfl_xor(part, 32);
        if (lg == 0) qrel[wq + lc][NV - 1] = f2b(part);
    }

    // register-cached saturated rel values (clamp hits these for ~85% of keys)
    float relL[4], relR[4];
#pragma unroll
    for (int r = 0; r < 4; ++r) {
        int lq = wq + lg * 4 + r;
        relL[r] = b2f(qrel[lq][0]);
        relR[r] = b2f(qrel[lq][2 * RR]);
    }

    const int tile0 = qstm ? 8 : 0;
    float lsum[4] = {0.f, 0.f, 0.f, 0.f};
    v4f o[4];
#pragma unroll
    for (int dt = 0; dt < 4; ++dt) o[dt] = (v4f){0.f, 0.f, 0.f, 0.f};
    float e0l[4] = {0.f, 0.f, 0.f, 0.f};
    float e1l[4] = {0.f, 0.f, 0.f, 0.f};
    float* arow = attn_out + ((size_t)bh * SS + qbase) * SS;

    // ---- single fused sweep: scores -> unnorm exp -> stage/bins -> PV ----
    for (int kt = tile0; kt < 10; ++kt) {
        const ushort* kbase = kb + bhoff + (size_t)(kt * 64) * HD;
        const bool dorel = qstm || (kt < 8);
        const uint32_t nib = (uint32_t)(mkbits >> (kt * 4));
#pragma unroll
        for (int sub = 0; sub < 4; ++sub) {
            v8s bk0 = *reinterpret_cast<const v8s*>(&kbase[(sub * 16 + lc) * HD + lg * 8]);
            v8s bk1 = *reinterpret_cast<const v8s*>(&kbase[(sub * 16 + lc) * HD + 32 + lg * 8]);
            v4f c4 = {0.f, 0.f, 0.f, 0.f};
            c4 = __builtin_amdgcn_mfma_f32_16x16x32_bf16(aq0, bk0, c4, 0, 0, 0);
            c4 = __builtin_amdgcn_mfma_f32_16x16x32_bf16(aq1, bk1, c4, 0, 0, 0);
            int kg = kt * 64 + sub * 16 + lc;
            const bool mk = (nib >> sub) & 1;
#pragma unroll
            for (int r = 0; r < 4; ++r) {
                int lq = wq + lg * 4 + r;
                int dlt = kg - (qbase + lq);
                bool inband = dorel && (dlt > -RR) && (dlt < RR);
                float val = c4[r];
                if (dorel) {
                    float relv;
                    if (inband) relv = b2f(qrel[lq][dlt + RR]);
                    else        relv = (dlt <= -RR) ? relL[r] : relR[r];
                    val += relv;
                }
                if (mk) val = NEGINF;
                float p = __expf(val);              // UNNORMALIZED
                lsum[r] += p;
                ushort pb = f2b(p);
                Pfull[lq][kt * 64 + sub * 16 + lc] = pb;
                if (inband) wbin[lq][dlt + RR] = pb;
                else if (dorel) {
                    if (dlt <= -RR) e0l[r] += p;
                    else            e1l[r] += p;
                }
            }
        }
        // PV for this tile with unnormalized P (o scaled by invl at the end)
        v8s ap0 = *reinterpret_cast<const v8s*>(&Pfull[wq + lc][kt * 64 + lg * 8]);
        v8s ap1 = *reinterpret_cast<const v8s*>(&Pfull[wq + lc][kt * 64 + 32 + lg * 8]);
        const ushort* vbase = vtb + bhoff + kt * 64;
#pragma unroll
        for (int dt = 0; dt < 4; ++dt) {
            v8s bv0 = *reinterpret_cast<const v8s*>(&vbase[(size_t)(dt * 16 + lc) * SS + lg * 8]);
            v8s bv1 = *reinterpret_cast<const v8s*>(&vbase[(size_t)(dt * 16 + lc) * SS + 32 + lg * 8]);
            o[dt] = __builtin_amdgcn_mfma_f32_16x16x32_bf16(ap0, bv0, o[dt], 0, 0, 0);
            o[dt] = __builtin_amdgcn_mfma_f32_16x16x32_bf16(ap1, bv1, o[dt], 0, 0, 0);
        }
    }

    // row-sum reduce -> invl; broadcast per-row through linv (wave-own rows)
    float invl[4];
#pragma unroll
    for (int r = 0; r < 4; ++r) {
        float s = lsum[r];
        s += __shfl_xor(s, 1); s += __shfl_xor(s, 2);
        s += __shfl_xor(s, 4); s += __shfl_xor(s, 8);
        invl[r] = 1.f / s;
        if (lc == 0) linv[wq + lg * 4 + r] = invl[r];
    }

    // edge-bin reduce (over the 16 col-lanes) + write; e1 kept for stok fixup
    float e1s[4];
#pragma unroll
    for (int r = 0; r < 4; ++r) {
        float s0 = e0l[r], s1 = e1l[r];
        s0 += __shfl_xor(s0, 1); s0 += __shfl_xor(s0, 2);
        s0 += __shfl_xor(s0, 4); s0 += __shfl_xor(s0, 8);
        s1 += __shfl_xor(s1, 1); s1 += __shfl_xor(s1, 2);
        s1 += __shfl_xor(s1, 4); s1 += __shfl_xor(s1, 8);
        e1s[r] = s1;
        if (lc == 0) {
            wbin[wq + lg * 4 + r][0] = f2b(s0);
            if (qstm) wbin[wq + lg * 4 + r][32] = f2b(s1);
        }
    }

    // ---- dense normalize+write of the attn tensor (pure streaming) ----
    for (int kt = tile0; kt < 10; ++kt) {
#pragma unroll
        for (int rr = 0; rr < 4; ++rr) {
            int row = wq + rr * 4 + lg;
            float iv = linv[row];
            ushort4 pk = *reinterpret_cast<ushort4*>(&Pfull[row][kt * 64 + lc * 4]);
            float4 pv4;
            pv4.x = b2f(pk.x) * iv;
            pv4.y = b2f(pk.y) * iv;
            pv4.z = b2f(pk.z) * iv;
            pv4.w = b2f(pk.w) * iv;
            *reinterpret_cast<float4*>(&arow[(size_t)row * SS + kt * 64 + lc * 4]) = pv4;
        }
    }

    // ---- rel-v virtual tile: stage relv^T into a [64][72] view of Pfull ----
    __syncthreads();
    {
        ushort* Rv = &Pfull[0][0];
        const float* tabv = qstm ? smv : relv;
        for (int idx = t; idx < 64 * 64; idx += 128) {
            int d = idx >> 6, v = idx & 63;
            float f = (v < NV) ? tabv[(size_t)v * HD + d] : 0.f;
            Rv[d * 72 + v] = f2b(f);
        }
    }
    __syncthreads();
    {
        const ushort* Rv = &Pfull[0][0];
        v8s aw0 = *reinterpret_cast<const v8s*>(&wbin[wq + lc][lg * 8]);
        v8s aw1 = *reinterpret_cast<const v8s*>(&wbin[wq + lc][32 + lg * 8]);
#pragma unroll
        for (int dt = 0; dt < 4; ++dt) {
            v8s bv0 = *reinterpret_cast<const v8s*>(&Rv[(dt * 16 + lc) * 72 + lg * 8]);
            v8s bv1 = *reinterpret_cast<const v8s*>(&Rv[(dt * 16 + lc) * 72 + 32 + lg * 8]);
            o[dt] = __builtin_amdgcn_mfma_f32_16x16x32_bf16(aw0, bv0, o[dt], 0, 0, 0);
            o[dt] = __builtin_amdgcn_mfma_f32_16x16x32_bf16(aw1, bv1, o[dt], 0, 0, 0);
        }
        if (!qstm) {   // rank-1 fixup for bin v=64 (register-local: rows match)
#pragma unroll
            for (int dt = 0; dt < 4; ++dt)
#pragma unroll
                for (int r = 0; r < 4; ++r)
                    o[dt][r] += e1s[r] * relv[(size_t)64 * HD + dt * 16 + lc];
        }
    }

    // normalize o and write ctx as bf16 hi/lo [b][s][h*64+d]
#pragma unroll
    for (int dt = 0; dt < 4; ++dt)
#pragma unroll
        for (int r = 0; r < 4; ++r) {
            int gq = qbase + wq + lg * 4 + r;
            size_t idx = ((size_t)b * SS + gq) * DIM + h * HD + dt * 16 + lc;
            float v = o[dt][r] * invl[r];
            ushort hi = f2b(v);
            ctxh[idx] = hi;
            ctxl[idx] = f2b(v - b2f(hi));
        }
}

// ---------------------------------------------------------------------------
extern "C" void kernel_launch(void* const* d_in, const int* in_sizes, int n_in,
                              void* d_out, int out_size, void* d_ws, size_t ws_size,
                              hipStream_t stream)
{
    const float*   stok  = (const float*)d_in[0];
    const float*   stm   = (const float*)d_in[1];
    const uint8_t* mtok  = (const uint8_t*)d_in[2];
    const uint8_t* mstm  = (const uint8_t*)d_in[3];
    const float*   qkv_w = (const float*)d_in[4];
    const float*   qkv_b = (const float*)d_in[5];
    const float*   out_w = (const float*)d_in[6];
    const float*   out_b = (const float*)d_in[7];
    const float*   relk  = (const float*)d_in[8];
    const float*   relv  = (const float*)d_in[9];
    const float*   smk   = (const float*)d_in[10];
    const float*   smv   = (const float*)d_in[11];

    float* out_final = (float*)d_out;
    float* out_attn  = out_final + (size_t)BB * SS * DIM;

    const size_t SZ = (size_t)BB * HH * SS * HD;           // 5,242,880
    ushort* qb16 = (ushort*)d_ws;
    ushort* kb16 = qb16 + SZ;
    ushort* vt16 = kb16 + SZ;
    ushort* xb16 = vt16 + SZ;                              // 5,242,880 ushorts
    ushort* wb16 = xb16 + SZ;                              // 3,145,728 ushorts
    ushort* ctxh = wb16 + (size_t)3 * DIM * DIM;
    ushort* ctxl = ctxh + SZ;
    ushort* woh  = ctxl + SZ;                              // 1,048,576 ushorts
    ushort* wol  = woh + (size_t)DIM * DIM;

    cvt_bf16<<<dim3(9216), dim3(256), 0, stream>>>(stok, stm, qkv_w, out_w,
                                                   xb16, wb16, woh, wol);
    gemm_qkv_mfma<<<dim3(960), dim3(256), 0, stream>>>(xb16, wb16, qkv_b, qb16, kb16, vt16);
    attn_mfma<<<dim3(2560), dim3(128), 0, stream>>>(qb16, kb16, vt16, mtok, mstm,
                                                    relk, relv, smk, smv, out_attn, ctxh, ctxl);
    gemm_out_mfma<<<dim3(640), dim3(256), 0, stream>>>(ctxh, ctxl, woh, wol, out_b, out_final);
}

// Round 13
// 306.287 us; speedup vs baseline: 1.4950x; 1.4345x over previous
//
#include <hip/hip_runtime.h>
#include <stdint.h>

// Problem constants
#define BB    8
#define HH    16
#define SS    640
#define STOK  512
#define STMN  128
#define HD    64
#define DIM   1024
#define NEGINF (-1e18f)

typedef short v8s __attribute__((ext_vector_type(8)));
typedef float v4f __attribute__((ext_vector_type(4)));

static __device__ __forceinline__ ushort f2b(float f) {
    union { float f; uint32_t u; } x; x.f = f;
    uint32_t u = (x.u + 0x7FFFu + ((x.u >> 16) & 1u)) >> 16;
    return (ushort)u;
}
static __device__ __forceinline__ float b2f(ushort h) {
    union { uint32_t u; float f; } x; x.u = ((uint32_t)h) << 16;
    return x.f;
}

// async global->LDS, 16 B per lane; dest is wave-uniform base + lane*16
static __device__ __forceinline__ void gld16(const ushort* g, ushort* l) {
    __builtin_amdgcn_global_load_lds(
        (const __attribute__((address_space(1))) unsigned int*)g,
        (__attribute__((address_space(3))) unsigned int*)l, 16, 0, 0);
}

// ---------------------------------------------------------------------------
// Kernel A0: convert x (stok||stm, [5120][1024]) and qkv_w ([3072][1024]) to
// bf16; split out_w ([1024][1024]) into bf16 hi/lo pair.  Pure streaming.
// ---------------------------------------------------------------------------
__global__ __launch_bounds__(256) void cvt_bf16(
    const float* __restrict__ stok, const float* __restrict__ stm,
    const float* __restrict__ W, const float* __restrict__ Wo,
    ushort* __restrict__ xb, ushort* __restrict__ Wb,
    ushort* __restrict__ Woh, ushort* __restrict__ Wol)
{
    const int i = blockIdx.x * 256 + threadIdx.x;
    const int XG = 5120 * 256;                      // float4-groups in x
    const int WG = 3072 * 256;                      // float4-groups in qkv_w
    if (i < XG + WG) {
        float4 v; ushort* dst;
        if (i < XG) {
            int row = i >> 8, g = i & 255;
            int b = row / SS, s = row % SS;
            const float* src = (s < STOK)
                ? stok + ((size_t)b * STOK + s) * DIM
                : stm  + ((size_t)b * STMN + (s - STOK)) * DIM;
            v = *reinterpret_cast<const float4*>(src + g * 4);
            dst = xb + (size_t)row * DIM + g * 4;
        } else {
            int j = i - XG;
            int row = j >> 8, g = j & 255;
            v = *reinterpret_cast<const float4*>(W + (size_t)row * DIM + g * 4);
            dst = Wb + (size_t)row * DIM + g * 4;
        }
        ushort4 o;
        o.x = f2b(v.x); o.y = f2b(v.y); o.z = f2b(v.z); o.w = f2b(v.w);
        *reinterpret_cast<ushort4*>(dst) = o;
    } else {
        int j = i - XG - WG;
        int row = j >> 8, g = j & 255;
        float4 v = *reinterpret_cast<const float4*>(Wo + (size_t)row * DIM + g * 4);
        ushort4 hi, lo;
        hi.x = f2b(v.x); lo.x = f2b(v.x - b2f(hi.x));
        hi.y = f2b(v.y); lo.y = f2b(v.y - b2f(hi.y));
        hi.z = f2b(v.z); lo.z = f2b(v.z - b2f(hi.z));
        hi.w = f2b(v.w); lo.w = f2b(v.w - b2f(hi.w));
        *reinterpret_cast<ushort4*>(&Woh[(size_t)row * DIM + g * 4]) = hi;
        *reinterpret_cast<ushort4*>(&Wol[(size_t)row * DIM + g * 4]) = lo;
    }
}

// ---------------------------------------------------------------------------
// Kernel A: QKV projection, m97-style LDS-staged MFMA GEMM.
// Tile 64x128 (1920 blocks), BK=32, 4 waves (2x2), wave = 32x64 = 2x4 frags.
// Staging via global_load_lds (linear dest) with XOR-swizzled SOURCE chunks;
// ds_read applies the same swizzle -> conflict-free (2-way max).
// Epilogue: bf16 q[bh][s][d] (pre-scaled 1/8), k[bh][s][d], vT[bh][d][s].
// ---------------------------------------------------------------------------
__global__ __launch_bounds__(256) void gemm_qkv_mfma(
    const ushort* __restrict__ xb, const ushort* __restrict__ Wb,
    const float* __restrict__ bias,
    ushort* __restrict__ qb, ushort* __restrict__ kb, ushort* __restrict__ vtb)
{
    __shared__ __align__(16) ushort As[64 * 32];     // 4 KB
    __shared__ __align__(16) ushort Bs[128 * 32];    // 8 KB
    const int t = threadIdx.x, lane = t & 63, w = t >> 6;
    // nt-major XCD swizzle: 1920 = 8*240; each XCD owns 3 n-panels (W L2-res)
    const int swz = ((blockIdx.x & 7) * 240) + (blockIdx.x >> 3);
    const int nt = swz / 80, mt = swz % 80;
    const int mb = mt * 64, nb = nt * 128;
    const int wm = (w >> 1) * 32, wn = (w & 1) * 64;
    const int lg = lane >> 4, lc = lane & 15;

    // staging assignments (chunk = 16 B = 8 ushorts)
    // A: 256 chunks (1/thread), B: 512 chunks (2/thread)
    const int ra = t >> 2, pa = t & 3;
    const ushort* gA = xb + (size_t)(mb + ra) * DIM + (pa ^ ((ra >> 1) & 3)) * 8;
    ushort* lA = As + (w * 64) * 8;
    const ushort* gB[2]; ushort* lB[2];
#pragma unroll
    for (int i = 0; i < 2; ++i) {
        int c = t + i * 256, rb = c >> 2, pb = c & 3;
        gB[i] = Wb + (size_t)(nb + rb) * DIM + (pb ^ ((rb >> 1) & 3)) * 8;
        lB[i] = Bs + (i * 256 + w * 64) * 8;
    }

    v4f acc[2][4];
#pragma unroll
    for (int i = 0; i < 2; ++i)
#pragma unroll
        for (int j = 0; j < 4; ++j) acc[i][j] = (v4f){0.f, 0.f, 0.f, 0.f};

    for (int kt = 0; kt < 32; ++kt) {
        const int ko = kt * 32;
        __syncthreads();                 // LDS free (prev reads done)
        gld16(gA + ko, lA);
        gld16(gB[0] + ko, lB[0]);
        gld16(gB[1] + ko, lB[1]);
        __syncthreads();                 // vmcnt(0) drained before barrier
        v8s af[2], bf[4];
#pragma unroll
        for (int i = 0; i < 2; ++i) {
            int ar = wm + i * 16 + lc;
            af[i] = *reinterpret_cast<const v8s*>(&As[ar * 32 + (lg ^ ((ar >> 1) & 3)) * 8]);
        }
#pragma unroll
        for (int j = 0; j < 4; ++j) {
            int br = wn + j * 16 + lc;
            bf[j] = *reinterpret_cast<const v8s*>(&Bs[br * 32 + (lg ^ ((br >> 1) & 3)) * 8]);
        }
#pragma unroll
        for (int i = 0; i < 2; ++i)
#pragma unroll
            for (int j = 0; j < 4; ++j)
                acc[i][j] = __builtin_amdgcn_mfma_f32_16x16x32_bf16(af[i], bf[j], acc[i][j], 0, 0, 0);
    }

    const int nregion = nb >> 10;                  // 0=q 1=k 2=v
    if (nregion < 2) {
        ushort* dst = nregion ? kb : qb;
        const float scale = nregion ? 1.0f : 0.125f;
#pragma unroll
        for (int j = 0; j < 4; ++j) {
            int n = nb + wn + j * 16 + lc;
            int nn = n & 1023, h = nn >> 6, d = nn & 63;
            float bi = bias[n];
#pragma unroll
            for (int i = 0; i < 2; ++i) {
                int m0 = mb + wm + i * 16 + lg * 4;
                int b = m0 / SS, s0 = m0 % SS;
                size_t base = (((size_t)b * HH + h) * SS + s0) * HD + d;
#pragma unroll
                for (int r = 0; r < 4; ++r)
                    dst[base + (size_t)r * HD] = f2b((acc[i][j][r] + bi) * scale);
            }
        }
    } else {
#pragma unroll
        for (int j = 0; j < 4; ++j) {
            int n = nb + wn + j * 16 + lc;
            int nn = n & 1023, h = nn >> 6, d = nn & 63;
            float bi = bias[n];
#pragma unroll
            for (int i = 0; i < 2; ++i) {
                int m0 = mb + wm + i * 16 + lg * 4;   // 4 consecutive s, same b
                int b = m0 / SS, s0 = m0 % SS;
                ushort4 pk;
                pk.x = f2b(acc[i][j][0] + bi);
                pk.y = f2b(acc[i][j][1] + bi);
                pk.z = f2b(acc[i][j][2] + bi);
                pk.w = f2b(acc[i][j][3] + bi);
                *reinterpret_cast<ushort4*>(
                    &vtb[(((size_t)b * HH + h) * HD + d) * SS + s0]) = pk;
            }
        }
    }
}

// ---------------------------------------------------------------------------
// Kernel C: out projection, LDS-staged double-bf16 MFMA GEMM.
// Tile 64x64 (1280 blocks), BK=32, 4 waves (2x2), wave = 32x32 = 2x2 frags,
// fused hi/lo passes (12 MFMA/step).  nt-major XCD swizzle: W hi/lo panels
// (512 KB/XCD) stay L2-resident; ctx streams via L3.
// ---------------------------------------------------------------------------
__global__ __launch_bounds__(256) void gemm_out_mfma(
    const ushort* __restrict__ Xh, const ushort* __restrict__ Xl,
    const ushort* __restrict__ Wh, const ushort* __restrict__ Wl,
    const float* __restrict__ bias, float* __restrict__ out)
{
    __shared__ __align__(16) ushort Ah[64 * 32];
    __shared__ __align__(16) ushort Al[64 * 32];
    __shared__ __align__(16) ushort Bh[64 * 32];
    __shared__ __align__(16) ushort Bl[64 * 32];
    const int t = threadIdx.x, lane = t & 63, w = t >> 6;
    // nt-major: 1280 = 8*160; each XCD owns 2 n-panels
    const int swz = ((blockIdx.x & 7) * 160) + (blockIdx.x >> 3);
    const int nt = swz / 80, mt = swz % 80;
    const int mb = mt * 64, nb = nt * 64;
    const int wm = (w >> 1) * 32, wn = (w & 1) * 32;
    const int lg = lane >> 4, lc = lane & 15;

    // 256 chunks per tile -> 1 chunk/thread/tile
    const int rr = t >> 2, pp = t & 3;
    const size_t goff = (size_t)rr * DIM + (pp ^ ((rr >> 1) & 3)) * 8;
    const ushort* gAh = Xh + (size_t)mb * DIM + goff;
    const ushort* gAl = Xl + (size_t)mb * DIM + goff;
    const ushort* gBh = Wh + (size_t)nb * DIM + goff;
    const ushort* gBl = Wl + (size_t)nb * DIM + goff;
    ushort* lbase_off;
    const int wchunk = (w * 64) * 8;

    v4f acc[2][2];
#pragma unroll
    for (int i = 0; i < 2; ++i)
#pragma unroll
        for (int j = 0; j < 2; ++j) acc[i][j] = (v4f){0.f, 0.f, 0.f, 0.f};

    for (int kt = 0; kt < 32; ++kt) {
        const int ko = kt * 32;
        __syncthreads();
        gld16(gAh + ko, Ah + wchunk);
        gld16(gAl + ko, Al + wchunk);
        gld16(gBh + ko, Bh + wchunk);
        gld16(gBl + ko, Bl + wchunk);
        __syncthreads();
        v8s ahf[2], alf[2], bhf[2], blf[2];
#pragma unroll
        for (int i = 0; i < 2; ++i) {
            int ar = wm + i * 16 + lc;
            int ao = ar * 32 + (lg ^ ((ar >> 1) & 3)) * 8;
            ahf[i] = *reinterpret_cast<const v8s*>(&Ah[ao]);
            alf[i] = *reinterpret_cast<const v8s*>(&Al[ao]);
            int br = wn + i * 16 + lc;
            int bo = br * 32 + (lg ^ ((br >> 1) & 3)) * 8;
            bhf[i] = *reinterpret_cast<const v8s*>(&Bh[bo]);
            blf[i] = *reinterpret_cast<const v8s*>(&Bl[bo]);
        }
#pragma unroll
        for (int i = 0; i < 2; ++i)
#pragma unroll
            for (int j = 0; j < 2; ++j)
                acc[i][j] = __builtin_amdgcn_mfma_f32_16x16x32_bf16(ahf[i], bhf[j], acc[i][j], 0, 0, 0);
#pragma unroll
        for (int i = 0; i < 2; ++i)
#pragma unroll
            for (int j = 0; j < 2; ++j)
                acc[i][j] = __builtin_amdgcn_mfma_f32_16x16x32_bf16(alf[i], bhf[j], acc[i][j], 0, 0, 0);
#pragma unroll
        for (int i = 0; i < 2; ++i)
#pragma unroll
            for (int j = 0; j < 2; ++j)
                acc[i][j] = __builtin_amdgcn_mfma_f32_16x16x32_bf16(ahf[i], blf[j], acc[i][j], 0, 0, 0);
    }
    (void)lbase_off;

#pragma unroll
    for (int j = 0; j < 2; ++j) {
        int n = nb + wn + j * 16 + lc;
        float bi = bias[n];
#pragma unroll
        for (int i = 0; i < 2; ++i) {
            int m0 = mb + wm + i * 16 + lg * 4;
#pragma unroll
            for (int r = 0; r < 4; ++r)
                out[(size_t)(m0 + r) * DIM + n] = acc[i][j][r] + bi;
        }
    }
}

// ---------------------------------------------------------------------------
// Kernel B: SINGLE-PASS barrier-free MFMA attention (deferred normalization).
// Unchanged from round 12 (182 us).
// ---------------------------------------------------------------------------
__global__ __launch_bounds__(128) void attn_mfma(
    const ushort* __restrict__ qb, const ushort* __restrict__ kb,
    const ushort* __restrict__ vtb,
    const uint8_t* __restrict__ mtok, const uint8_t* __restrict__ mstm,
    const float* __restrict__ relk, const float* __restrict__ relv,
    const float* __restrict__ smk,  const float* __restrict__ smv,
    float* __restrict__ attn_out,
    ushort* __restrict__ ctxh, ushort* __restrict__ ctxl)
{
    __shared__ ushort qrel[32][72];
    __shared__ ushort Pfull[32][648];   // unnormalized exp(score), bf16
    __shared__ ushort wbin[32][72];
    __shared__ float  linv[32];

    const int t    = threadIdx.x;
    const int lane = t & 63, w = t >> 6;
    const int swz  = ((blockIdx.x & 7) * 320) + (blockIdx.x >> 3);  // XCD-contiguous
    const int qt = swz % 20, bh = swz / 20;
    const int b = bh >> 4, h = bh & 15;
    const int qbase = qt * 32;
    const bool qstm = (qt >= 16);
    const size_t bhoff = (size_t)bh * (SS * HD);
    const int wq = w * 16, lg = lane >> 4, lc = lane & 15;
    const int RR = qstm ? 16 : 32;
    const int NV = qstm ? 33 : 65;
    const float* tabk = qstm ? smk : relk;

    for (int i = lane; i < 16 * 36; i += 64) {
        int r = i / 36, c = i - r * 36;
        *reinterpret_cast<uint32_t*>(&wbin[wq + r][c * 2]) = 0u;
    }

    if (qstm) {
        float4 z = make_float4(0.f, 0.f, 0.f, 0.f);
        float* dst = attn_out + ((size_t)bh * SS + qbase) * SS;
        for (int idx = t; idx < 32 * 128; idx += 128) {
            int r = idx >> 7, c4 = idx & 127;
            *reinterpret_cast<float4*>(&dst[(size_t)r * SS + c4 * 4]) = z;
        }
    }

    uint64_t mkbits = 0;
#pragma unroll
    for (int kt = 0; kt < 10; ++kt)
#pragma unroll
        for (int sub = 0; sub < 4; ++sub) {
            int kg = kt * 64 + sub * 16 + lc;
            uint8_t m = (kg < STOK) ? mtok[b * STOK + kg] : mstm[b * STMN + kg - STOK];
            mkbits |= ((uint64_t)(m ? 1u : 0u)) << (kt * 4 + sub);
        }

    const int qrow = qbase + wq + lc;
    v8s aq0 = *reinterpret_cast<const v8s*>(&qb[bhoff + (size_t)qrow * HD + lg * 8]);
    v8s aq1 = *reinterpret_cast<const v8s*>(&qb[bhoff + (size_t)qrow * HD + 32 + lg * 8]);

    {
        const int ndt = qstm ? 2 : 4;
        for (int dt = 0; dt < ndt; ++dt) {
            const float* rp = tabk + (size_t)(dt * 16 + lc) * HD;
            v8s bk0, bk1;
#pragma unroll
            for (int j = 0; j < 8; ++j) {
                bk0[j] = (short)f2b(rp[lg * 8 + j]);
                bk1[j] = (short)f2b(rp[32 + lg * 8 + j]);
            }
            v4f c4 = {0.f, 0.f, 0.f, 0.f};
            c4 = __builtin_amdgcn_mfma_f32_16x16x32_bf16(aq0, bk0, c4, 0, 0, 0);
            c4 = __builtin_amdgcn_mfma_f32_16x16x32_bf16(aq1, bk1, c4, 0, 0, 0);
#pragma unroll
            for (int r = 0; r < 4; ++r)
                qrel[wq + lg * 4 + r][dt * 16 + lc] = f2b(c4[r]);
        }
        const float* rp = tabk + (size_t)(NV - 1) * HD;
        float part = 0.f;
#pragma unroll
        for (int j = 0; j < 8; ++j) {
            part += b2f((ushort)aq0[j]) * rp[lg * 8 + j];
            part += b2f((ushort)aq1[j]) * rp[32 + lg * 8 + j];
        }
        part += __shfl_xor(part, 16);
        part += __shfl_xor(part, 32);
        if (lg == 0) qrel[wq + lc][NV - 1] = f2b(part);
    }

    float relL[4], relR[4];
#pragma unroll
    for (int r = 0; r < 4; ++r) {
        int lq = wq + lg * 4 + r;
        relL[r] = b2f(qrel[lq][0]);
        relR[r] = b2f(qrel[lq][2 * RR]);
    }

    const int tile0 = qstm ? 8 : 0;
    float lsum[4] = {0.f, 0.f, 0.f, 0.f};
    v4f o[4];
#pragma unroll
    for (int dt = 0; dt < 4; ++dt) o[dt] = (v4f){0.f, 0.f, 0.f, 0.f};
    float e0l[4] = {0.f, 0.f, 0.f, 0.f};
    float e1l[4] = {0.f, 0.f, 0.f, 0.f};
    float* arow = attn_out + ((size_t)bh * SS + qbase) * SS;

    for (int kt = tile0; kt < 10; ++kt) {
        const ushort* kbase = kb + bhoff + (size_t)(kt * 64) * HD;
        const bool dorel = qstm || (kt < 8);
        const uint32_t nib = (uint32_t)(mkbits >> (kt * 4));
#pragma unroll
        for (int sub = 0; sub < 4; ++sub) {
            v8s bk0 = *reinterpret_cast<const v8s*>(&kbase[(sub * 16 + lc) * HD + lg * 8]);
            v8s bk1 = *reinterpret_cast<const v8s*>(&kbase[(sub * 16 + lc) * HD + 32 + lg * 8]);
            v4f c4 = {0.f, 0.f, 0.f, 0.f};
            c4 = __builtin_amdgcn_mfma_f32_16x16x32_bf16(aq0, bk0, c4, 0, 0, 0);
            c4 = __builtin_amdgcn_mfma_f32_16x16x32_bf16(aq1, bk1, c4, 0, 0, 0);
            int kg = kt * 64 + sub * 16 + lc;
            const bool mk = (nib >> sub) & 1;
#pragma unroll
            for (int r = 0; r < 4; ++r) {
                int lq = wq + lg * 4 + r;
                int dlt = kg - (qbase + lq);
                bool inband = dorel && (dlt > -RR) && (dlt < RR);
                float val = c4[r];
                if (dorel) {
                    float relv;
                    if (inband) relv = b2f(qrel[lq][dlt + RR]);
                    else        relv = (dlt <= -RR) ? relL[r] : relR[r];
                    val += relv;
                }
                if (mk) val = NEGINF;
                float p = __expf(val);              // UNNORMALIZED
                lsum[r] += p;
                ushort pb = f2b(p);
                Pfull[lq][kt * 64 + sub * 16 + lc] = pb;
                if (inband) wbin[lq][dlt + RR] = pb;
                else if (dorel) {
                    if (dlt <= -RR) e0l[r] += p;
                    else            e1l[r] += p;
                }
            }
        }
        v8s ap0 = *reinterpret_cast<const v8s*>(&Pfull[wq + lc][kt * 64 + lg * 8]);
        v8s ap1 = *reinterpret_cast<const v8s*>(&Pfull[wq + lc][kt * 64 + 32 + lg * 8]);
        const ushort* vbase = vtb + bhoff + kt * 64;
#pragma unroll
        for (int dt = 0; dt < 4; ++dt) {
            v8s bv0 = *reinterpret_cast<const v8s*>(&vbase[(size_t)(dt * 16 + lc) * SS + lg * 8]);
            v8s bv1 = *reinterpret_cast<const v8s*>(&vbase[(size_t)(dt * 16 + lc) * SS + 32 + lg * 8]);
            o[dt] = __builtin_amdgcn_mfma_f32_16x16x32_bf16(ap0, bv0, o[dt], 0, 0, 0);
            o[dt] = __builtin_amdgcn_mfma_f32_16x16x32_bf16(ap1, bv1, o[dt], 0, 0, 0);
        }
    }

    float invl[4];
#pragma unroll
    for (int r = 0; r < 4; ++r) {
        float s = lsum[r];
        s += __shfl_xor(s, 1); s += __shfl_xor(s, 2);
        s += __shfl_xor(s, 4); s += __shfl_xor(s, 8);
        invl[r] = 1.f / s;
        if (lc == 0) linv[wq + lg * 4 + r] = invl[r];
    }

    float e1s[4];
#pragma unroll
    for (int r = 0; r < 4; ++r) {
        float s0 = e0l[r], s1 = e1l[r];
        s0 += __shfl_xor(s0, 1); s0 += __shfl_xor(s0, 2);
        s0 += __shfl_xor(s0, 4); s0 += __shfl_xor(s0, 8);
        s1 += __shfl_xor(s1, 1); s1 += __shfl_xor(s1, 2);
        s1 += __shfl_xor(s1, 4); s1 += __shfl_xor(s1, 8);
        e1s[r] = s1;
        if (lc == 0) {
            wbin[wq + lg * 4 + r][0] = f2b(s0);
            if (qstm) wbin[wq + lg * 4 + r][32] = f2b(s1);
        }
    }

    for (int kt = tile0; kt < 10; ++kt) {
#pragma unroll
        for (int rr = 0; rr < 4; ++rr) {
            int row = wq + rr * 4 + lg;
            float iv = linv[row];
            ushort4 pk = *reinterpret_cast<ushort4*>(&Pfull[row][kt * 64 + lc * 4]);
            float4 pv4;
            pv4.x = b2f(pk.x) * iv;
            pv4.y = b2f(pk.y) * iv;
            pv4.z = b2f(pk.z) * iv;
            pv4.w = b2f(pk.w) * iv;
            *reinterpret_cast<float4*>(&arow[(size_t)row * SS + kt * 64 + lc * 4]) = pv4;
        }
    }

    __syncthreads();
    {
        ushort* Rv = &Pfull[0][0];
        const float* tabv = qstm ? smv : relv;
        for (int idx = t; idx < 64 * 64; idx += 128) {
            int d = idx >> 6, v = idx & 63;
            float f = (v < NV) ? tabv[(size_t)v * HD + d] : 0.f;
            Rv[d * 72 + v] = f2b(f);
        }
    }
    __syncthreads();
    {
        const ushort* Rv = &Pfull[0][0];
        v8s aw0 = *reinterpret_cast<const v8s*>(&wbin[wq + lc][lg * 8]);
        v8s aw1 = *reinterpret_cast<const v8s*>(&wbin[wq + lc][32 + lg * 8]);
#pragma unroll
        for (int dt = 0; dt < 4; ++dt) {
            v8s bv0 = *reinterpret_cast<const v8s*>(&Rv[(dt * 16 + lc) * 72 + lg * 8]);
            v8s bv1 = *reinterpret_cast<const v8s*>(&Rv[(dt * 16 + lc) * 72 + 32 + lg * 8]);
            o[dt] = __builtin_amdgcn_mfma_f32_16x16x32_bf16(aw0, bv0, o[dt], 0, 0, 0);
            o[dt] = __builtin_amdgcn_mfma_f32_16x16x32_bf16(aw1, bv1, o[dt], 0, 0, 0);
        }
        if (!qstm) {
#pragma unroll
            for (int dt = 0; dt < 4; ++dt)
#pragma unroll
                for (int r = 0; r < 4; ++r)
                    o[dt][r] += e1s[r] * relv[(size_t)64 * HD + dt * 16 + lc];
        }
    }

#pragma unroll
    for (int dt = 0; dt < 4; ++dt)
#pragma unroll
        for (int r = 0; r < 4; ++r) {
            int gq = qbase + wq + lg * 4 + r;
            size_t idx = ((size_t)b * SS + gq) * DIM + h * HD + dt * 16 + lc;
            float v = o[dt][r] * invl[r];
            ushort hi = f2b(v);
            ctxh[idx] = hi;
            ctxl[idx] = f2b(v - b2f(hi));
        }
}

// ---------------------------------------------------------------------------
extern "C" void kernel_launch(void* const* d_in, const int* in_sizes, int n_in,
                              void* d_out, int out_size, void* d_ws, size_t ws_size,
                              hipStream_t stream)
{
    const float*   stok  = (const float*)d_in[0];
    const float*   stm   = (const float*)d_in[1];
    const uint8_t* mtok  = (const uint8_t*)d_in[2];
    const uint8_t* mstm  = (const uint8_t*)d_in[3];
    const float*   qkv_w = (const float*)d_in[4];
    const float*   qkv_b = (const float*)d_in[5];
    const float*   out_w = (const float*)d_in[6];
    const float*   out_b = (const float*)d_in[7];
    const float*   relk  = (const float*)d_in[8];
    const float*   relv  = (const float*)d_in[9];
    const float*   smk   = (const float*)d_in[10];
    const float*   smv   = (const float*)d_in[11];

    float* out_final = (float*)d_out;
    float* out_attn  = out_final + (size_t)BB * SS * DIM;

    const size_t SZ = (size_t)BB * HH * SS * HD;           // 5,242,880
    ushort* qb16 = (ushort*)d_ws;
    ushort* kb16 = qb16 + SZ;
    ushort* vt16 = kb16 + SZ;
    ushort* xb16 = vt16 + SZ;                              // 5,242,880 ushorts
    ushort* wb16 = xb16 + SZ;                              // 3,145,728 ushorts
    ushort* ctxh = wb16 + (size_t)3 * DIM * DIM;
    ushort* ctxl = ctxh + SZ;
    ushort* woh  = ctxl + SZ;                              // 1,048,576 ushorts
    ushort* wol  = woh + (size_t)DIM * DIM;

    cvt_bf16<<<dim3(9216), dim3(256), 0, stream>>>(stok, stm, qkv_w, out_w,
                                                   xb16, wb16, woh, wol);
    gemm_qkv_mfma<<<dim3(1920), dim3(256), 0, stream>>>(xb16, wb16, qkv_b, qb16, kb16, vt16);
    attn_mfma<<<dim3(2560), dim3(128), 0, stream>>>(qb16, kb16, vt16, mtok, mstm,
                                                    relk, relv, smk, smv, out_attn, ctxh, ctxl);
    gemm_out_mfma<<<dim3(1280), dim3(256), 0, stream>>>(ctxh, ctxl, woh, wol, out_b, out_final);
}